// Round 14
// baseline (133.236 us; speedup 1.0000x reference)
//
#include <hip/hip_runtime.h>
#include <hip/hip_fp16.h>
#include <hip/hip_cooperative_groups.h>

namespace cg = cooperative_groups;

namespace {

constexpr int NQ     = 14;
constexpr int NST    = 1 << NQ;
constexpr int BLOCK  = 512;
constexpr int NWAVES = BLOCK / 64;

// ---------------- compile-time GF(2) machinery (verified R9 passing build) ----------------
constexpr unsigned cparity(unsigned x){ x^=x>>8; x^=x>>4; x^=x>>2; x^=x>>1; return x&1u; }

struct Mat { unsigned row[NQ]; unsigned col[NQ]; };

constexpr Mat m_after(int nr){
  Mat m{};
  for(int p=0;p<NQ;++p){ m.row[p]=1u<<p; m.col[p]=1u<<p; }
  for(int l=0;l<nr;++l)
    for(int q=0;q<NQ;++q){
      int cq=(q==NQ-1)?NQ-1:q, tq=(q==NQ-1)?0:q+1;
      int Pc=NQ-1-cq, Pt=NQ-1-tq;
      m.row[Pt]^=m.row[Pc]; m.col[Pc]^=m.col[Pt];
    }
  return m;
}

constexpr Mat M1=m_after(1), M2=m_after(2), M3=m_after(3);
constexpr unsigned amask(int q){ return M1.col[NQ-1-q]; }
constexpr unsigned arow (int q){ return M1.row[NQ-1-q]; }
constexpr unsigned bmask(int q){ return M2.col[NQ-1-q]; }
constexpr unsigned brow (int q){ return M2.row[NQ-1-q]; }

constexpr int rank_of(const unsigned* v, int n){
  unsigned a[24]{};
  for(int i=0;i<n;++i) a[i]=v[i];
  int r=0;
  for(int bit=15;bit>=0;--bit){
    int p=-1;
    for(int i=r;i<n;++i){ if((a[i]>>bit)&1){ p=i; break; } }
    if(p<0) continue;
    unsigned t=a[r]; a[r]=a[p]; a[p]=t;
    for(int i=0;i<n;++i) if(i!=r && ((a[i]>>bit)&1)) a[i]^=a[r];
    ++r;
  }
  return r;
}

// ---- per-phase gate sets: K0 = L1 q0..9; K1 = L1 q10..13 + 6 L2; K2 = 8 L2 ----
struct Sel {
  int picked[6], wq[4], un[4];
  unsigned Gen[3][10];
  unsigned Row[3][10];
  unsigned BlanePi4[6];
  unsigned EJ4[NQ];
  int lq[3][10][2];
};

constexpr Sel make_sel(){
  Sel S{};
  unsigned cur[24]{}; int nc=0;
  for(int t=0;t<4;++t) cur[nc++]=amask(10+t);
  bool used[14]{}; int picked[14]{}; int np=0;
  for(int q=0;q<14 && np<10;++q){
    cur[nc]=bmask(q);
    if(rank_of(cur,nc+1)==nc+1){ ++nc; picked[np++]=q; used[q]=true; }
  }
  for(int i=0;i<6;++i) S.picked[i]=picked[i];
  for(int i=0;i<4;++i) S.wq[i]=picked[6+i];
  { int nu=0; for(int q=0;q<14;++q) if(!used[q]) S.un[nu++]=q; }
  for(int i=0;i<6;++i){ unsigned m=0;
    for(int t=0;t<4;++t) m |= cparity(brow(picked[i]) & amask(10+t))<<t;
    S.BlanePi4[i]=m; }
  for(int g=0;g<10;++g){ S.Gen[0][g]=amask(g);    S.Row[0][g]=arow(g);    S.lq[0][g][0]=1; S.lq[0][g][1]=g; }
  for(int g=0;g<4;++g) { S.Gen[1][g]=amask(10+g); S.Row[1][g]=arow(10+g); S.lq[1][g][0]=1; S.lq[1][g][1]=10+g; }
  for(int g=0;g<6;++g) { S.Gen[1][4+g]=bmask(picked[g]); S.Row[1][4+g]=brow(picked[g]);
                         S.lq[1][4+g][0]=2; S.lq[1][4+g][1]=picked[g]; }
  for(int g=0;g<4;++g) { S.Gen[2][g]=bmask(S.wq[g]); S.Row[2][g]=brow(S.wq[g]);
                         S.lq[2][g][0]=2; S.lq[2][g][1]=S.wq[g]; }
  for(int g=0;g<4;++g) { S.Gen[2][4+g]=bmask(S.un[g]); S.Row[2][4+g]=brow(S.un[g]);
                         S.lq[2][4+g][0]=2; S.lq[2][4+g][1]=S.un[g]; }
  { unsigned cc[24]{}; int n=0;
    for(int t=0;t<8;++t) cc[n++]=S.Gen[2][t];
    int pos=8;
    for(int p=0;p<14 && pos<10;++p){
      cc[n]=1u<<p;
      if(rank_of(cc,n+1)==n+1){ S.Gen[2][pos]=1u<<p; S.Row[2][pos]=0; ++n; ++pos; }
    } }
  for(int w=0;w<NQ;++w){
    unsigned R=M3.row[NQ-1-w]; unsigned mj=0;
    for(int t=0;t<4;++t) mj |= cparity(R & S.Gen[2][t])<<t;
    S.EJ4[w]=mj;
  }
  return S;
}
constexpr Sel SL = make_sel();
static_assert(rank_of(SL.Gen[0],10)==10, "K0 gens");
static_assert(rank_of(SL.Gen[1],10)==10, "K1 gens");
static_assert(rank_of(SL.Gen[2],10)==10, "K2 gens");

struct Ins { unsigned ins[10]; };
constexpr Ins make_ins(const unsigned* gen){
  unsigned a[10]{}; for(int i=0;i<10;++i) a[i]=gen[i];
  int piv[10]{}; int r=0;
  for(int bit=13;bit>=0;--bit){
    int p=-1;
    for(int i=r;i<10;++i){ if((a[i]>>bit)&1){ p=i; break; } }
    if(p<0) continue;
    unsigned t=a[r]; a[r]=a[p]; a[p]=t;
    for(int i=0;i<10;++i) if(i!=r && ((a[i]>>bit)&1)) a[i]^=a[r];
    piv[r++]=bit;
  }
  for(int i=0;i<10;++i) for(int j=i+1;j<10;++j)
    if(piv[j]<piv[i]){ int t=piv[i]; piv[i]=piv[j]; piv[j]=t; }
  Ins I{};
  for(int g=0;g<10;++g) I.ins[g]=(1u<<piv[g])-1u;
  return I;
}
constexpr Ins INS0=make_ins(SL.Gen[0]), INS1=make_ins(SL.Gen[1]), INS2=make_ins(SL.Gen[2]);

struct CJ16 { unsigned v[16]; };
constexpr CJ16 make_cj(const unsigned* gen){
  CJ16 c{};
  for(int j=0;j<16;++j){ unsigned s=0; for(int b=0;b<4;++b) if((j>>b)&1) s^=gen[b]; c.v[j]=s; }
  return c;
}
constexpr CJ16 CJ0=make_cj(SL.Gen[0]), CJ1=make_cj(SL.Gen[1]), CJ2=make_cj(SL.Gen[2]);

constexpr int gidx(int PH, int g){ return (SL.lq[PH][g][0]-1)*NQ + SL.lq[PH][g][1]; }
constexpr unsigned TMA = SL.Gen[0][0]|SL.Gen[0][1]|SL.Gen[0][2]|SL.Gen[0][3];

// ---------------- packed-f16 complex helpers (verified R13 passing build) ----------------
__device__ __forceinline__ __half2 H2(unsigned u){ return __builtin_bit_cast(__half2, u); }
__device__ __forceinline__ unsigned U32(__half2 h){ return __builtin_bit_cast(unsigned, h); }
__device__ __forceinline__ unsigned hswap(unsigned u){ return __builtin_amdgcn_alignbit(u, u, 16); }

__device__ __forceinline__ float2 cmul2(float2 a, float2 b){
  return make_float2(fmaf(a.x, b.x, -(a.y * b.y)),
                     fmaf(a.x, b.y,  a.y * b.x));
}

struct GC { unsigned e[8]; };
__device__ __forceinline__ GC load_gc(const unsigned* __restrict__ g){
  const uint4* p = reinterpret_cast<const uint4*>(g);
  uint4 q0=p[0], q1=p[1];
  GC c;
  c.e[0]=q0.x; c.e[1]=q0.y; c.e[2]=q0.z; c.e[3]=q0.w;
  c.e[4]=q1.x; c.e[5]=q1.y; c.e[6]=q1.z; c.e[7]=q1.w;
  return c;
}

__device__ __forceinline__ void gpair(__half2& r0, __half2& r1, const unsigned (&m)[8],
                                      __half2 a0, __half2 a1){
  __half2 a0s = H2(hswap(U32(a0))), a1s = H2(hswap(U32(a1)));
  r0 = __hfma2(H2(m[0]),a0, __hfma2(H2(m[1]),a0s, __hfma2(H2(m[2]),a1, __hmul2(H2(m[3]),a1s))));
  r1 = __hfma2(H2(m[4]),a0, __hfma2(H2(m[5]),a0s, __hfma2(H2(m[6]),a1, __hmul2(H2(m[7]),a1s))));
}

template<int CTRL>
__device__ __forceinline__ unsigned dppu(unsigned x){
  return (unsigned)__builtin_amdgcn_update_dpp(0, (int)x, CTRL, 0xF, 0xF, true);
}
__device__ __forceinline__ unsigned x32u(unsigned x, unsigned lane){
  auto r = __builtin_amdgcn_permlane32_swap(x, x, false, false);
  return (lane & 32u) ? (unsigned)r[0] : (unsigned)r[1];
}
__device__ __forceinline__ unsigned x16u(unsigned x, unsigned lane){
#if __has_builtin(__builtin_amdgcn_permlane16_swap)
  auto r = __builtin_amdgcn_permlane16_swap(x, x, false, false);
  return (lane & 16u) ? (unsigned)r[0] : (unsigned)r[1];
#else
  return (unsigned)__builtin_amdgcn_ds_swizzle((int)x, 0x401F);
#endif
}
template<int K>
__device__ __forceinline__ unsigned xpart_u32(unsigned x, unsigned lane){
  if constexpr (K==0) return dppu<0xB1>(x);
  else if constexpr (K==1) return dppu<0x4E>(x);
  else if constexpr (K==2) return (unsigned)__builtin_amdgcn_ds_swizzle((int)x,0x101F);
  else if constexpr (K==3) return dppu<0x128>(x);
  else if constexpr (K==4) return x16u(x,lane);
  else return x32u(x,lane);
}

template<int BIT>
__device__ __forceinline__ void reg_gate(__half2 (&a)[16], const GC& c, bool eps){
  unsigned m[8];
#pragma unroll
  for(int i=0;i<8;++i) m[i] = eps ? c.e[i^6] : c.e[i];
#pragma unroll
  for(int v=0; v<16; ++v){
    if(!((v>>BIT)&1)){
      int w = v | (1<<BIT);
      __half2 n0, n1;
      gpair(n0, n1, m, a[v], a[w]);
      a[v]=n0; a[w]=n1;
    }
  }
}

template<int XK, unsigned PI4>
__device__ __forceinline__ void lane_gate(__half2 (&a)[16], const GC& c, bool sel, unsigned lane){
  unsigned ka0x = sel?c.e[6]:c.e[0], ka0n = sel?c.e[7]:c.e[1];
  unsigned kb0x = sel?c.e[4]:c.e[2], kb0n = sel?c.e[5]:c.e[3];
  unsigned ka1x = sel?c.e[0]:c.e[6], ka1n = sel?c.e[1]:c.e[7];
  unsigned kb1x = sel?c.e[2]:c.e[4], kb1n = sel?c.e[3]:c.e[5];
  unsigned th[16];
#pragma unroll
  for(int j=0;j<16;++j) th[j] = xpart_u32<XK>(U32(a[j]), lane);
#pragma unroll
  for(int j=0;j<16;++j){
    bool pi = (__builtin_popcount(PI4 & (unsigned)j) & 1) != 0;
    unsigned kax = pi?ka1x:ka0x, kan = pi?ka1n:ka0n;
    unsigned kbx = pi?kb1x:kb0x, kbn = pi?kb1n:kb0n;
    __half2 as  = H2(hswap(U32(a[j])));
    __half2 ths = H2(hswap(th[j]));
    a[j] = __hfma2(H2(kax),a[j], __hfma2(H2(kan),as, __hfma2(H2(kbx),H2(th[j]), __hmul2(H2(kbn),ths))));
  }
}

__device__ __forceinline__ float xsum64(float v, unsigned lane){
  v += __int_as_float((int)dppu<0xB1>((unsigned)__float_as_int(v)));
  v += __int_as_float((int)dppu<0x4E>((unsigned)__float_as_int(v)));
  v += __int_as_float(__builtin_amdgcn_ds_swizzle(__float_as_int(v),0x101F));
  v += __int_as_float((int)dppu<0x128>((unsigned)__float_as_int(v)));
  v += __int_as_float((int)x16u((unsigned)__float_as_int(v), lane));
  v += __int_as_float((int)x32u((unsigned)__float_as_int(v), lane));
  return v;
}

template<int PH>
__device__ __forceinline__ unsigned coset_base(unsigned tid, int piece){
  constexpr Ins INS = (PH==0)?INS0:(PH==1)?INS1:INS2;
  unsigned e = (tid>>6) | ((unsigned)piece<<3);
#pragma unroll
  for(int g=0; g<10; ++g) e = ((e & ~INS.ins[g])<<1) | (e & INS.ins[g]);
  unsigned s0t = e;
#pragma unroll
  for(int k=0;k<6;++k) s0t ^= SL.Gen[PH][4+k] & (0u - ((tid>>k)&1u));
  return s0t;
}

template<int PH>
__device__ __forceinline__ void gates_of_phase(__half2 (&a)[16], const unsigned* __restrict__ Ut,
                                               unsigned s0t, unsigned lane){
  reg_gate<0>(a, load_gc(Ut+gidx(PH,0)*8), (__builtin_popcount(SL.Row[PH][0]&s0t)&1)!=0);
  reg_gate<1>(a, load_gc(Ut+gidx(PH,1)*8), (__builtin_popcount(SL.Row[PH][1]&s0t)&1)!=0);
  reg_gate<2>(a, load_gc(Ut+gidx(PH,2)*8), (__builtin_popcount(SL.Row[PH][2]&s0t)&1)!=0);
  reg_gate<3>(a, load_gc(Ut+gidx(PH,3)*8), (__builtin_popcount(SL.Row[PH][3]&s0t)&1)!=0);
  if constexpr (PH==0){
    lane_gate<0,0u>(a, load_gc(Ut+gidx(0,4)*8), (__builtin_popcount(SL.Row[0][4]&s0t)&1)!=0, lane);
    lane_gate<1,0u>(a, load_gc(Ut+gidx(0,5)*8), (__builtin_popcount(SL.Row[0][5]&s0t)&1)!=0, lane);
    lane_gate<2,0u>(a, load_gc(Ut+gidx(0,6)*8), (__builtin_popcount(SL.Row[0][6]&s0t)&1)!=0, lane);
    lane_gate<3,0u>(a, load_gc(Ut+gidx(0,7)*8), (__builtin_popcount(SL.Row[0][7]&s0t)&1)!=0, lane);
    lane_gate<4,0u>(a, load_gc(Ut+gidx(0,8)*8), (__builtin_popcount(SL.Row[0][8]&s0t)&1)!=0, lane);
    lane_gate<5,0u>(a, load_gc(Ut+gidx(0,9)*8), (__builtin_popcount(SL.Row[0][9]&s0t)&1)!=0, lane);
  } else if constexpr (PH==1){
    lane_gate<0,SL.BlanePi4[0]>(a, load_gc(Ut+gidx(1,4)*8), (__builtin_popcount(SL.Row[1][4]&s0t)&1)!=0, lane);
    lane_gate<1,SL.BlanePi4[1]>(a, load_gc(Ut+gidx(1,5)*8), (__builtin_popcount(SL.Row[1][5]&s0t)&1)!=0, lane);
    lane_gate<2,SL.BlanePi4[2]>(a, load_gc(Ut+gidx(1,6)*8), (__builtin_popcount(SL.Row[1][6]&s0t)&1)!=0, lane);
    lane_gate<3,SL.BlanePi4[3]>(a, load_gc(Ut+gidx(1,7)*8), (__builtin_popcount(SL.Row[1][7]&s0t)&1)!=0, lane);
    lane_gate<4,SL.BlanePi4[4]>(a, load_gc(Ut+gidx(1,8)*8), (__builtin_popcount(SL.Row[1][8]&s0t)&1)!=0, lane);
    lane_gate<5,SL.BlanePi4[5]>(a, load_gc(Ut+gidx(1,9)*8), (__builtin_popcount(SL.Row[1][9]&s0t)&1)!=0, lane);
  } else {
    lane_gate<0,0u>(a, load_gc(Ut+gidx(2,4)*8), (__builtin_popcount(SL.Row[2][4]&s0t)&1)!=0, lane);
    lane_gate<1,0u>(a, load_gc(Ut+gidx(2,5)*8), (__builtin_popcount(SL.Row[2][5]&s0t)&1)!=0, lane);
    lane_gate<2,0u>(a, load_gc(Ut+gidx(2,6)*8), (__builtin_popcount(SL.Row[2][6]&s0t)&1)!=0, lane);
    lane_gate<3,0u>(a, load_gc(Ut+gidx(2,7)*8), (__builtin_popcount(SL.Row[2][7]&s0t)&1)!=0, lane);
    // lane dims 4,5 are layout-only fillers: no gates
  }
}

// ---------------- single cooperative kernel ----------------
__global__ __launch_bounds__(BLOCK) void qsim_kernel(
    const float* __restrict__ x, const float* __restrict__ prm,
    unsigned* __restrict__ ws, float* __restrict__ out, int batch)
{
  __shared__ alignas(16) unsigned Utab[28*8];
  __shared__ float2 l0c[NQ][2];
  __shared__ float  red[NWAVES][NQ];

  const int bid = blockIdx.x;
  const int piece = (bid >= batch) ? 1 : 0;
  const int s = bid - piece*batch;
  const unsigned tid = threadIdx.x;
  const unsigned lane = tid & 63u;

  // ---- all 28 gate tables, packed f16 ----
  if(tid < 28){
    int t = tid;
    int l = 1 + t/NQ, q = t % NQ;
    float ax=prm[(l*NQ+q)*3+0], ay=prm[(l*NQ+q)*3+1], az=prm[(l*NQ+q)*3+2];
    float cx,sx,cy,sy,cz,sz;
    sincosf(0.5f*ax,&sx,&cx); sincosf(0.5f*ay,&sy,&cy); sincosf(0.5f*az,&sz,&cz);
    float2 M00=make_float2(cy*cx, sy*sx),  M01=make_float2(-sy*cx,-cy*sx);
    float2 M10=make_float2(sy*cx,-cy*sx),  M11=make_float2(cy*cx,-sy*sx);
    float2 ez =make_float2(cz,-sz), ezc=make_float2(cz,sz);
    float2 U00=cmul2(ez,M00), U01=cmul2(ez,M01), U10=cmul2(ezc,M10), U11=cmul2(ezc,M11);
    unsigned* U = &Utab[t*8];
    U[0]=U32(__floats2half2_rn( U00.x,U00.x)); U[1]=U32(__floats2half2_rn(-U00.y,U00.y));
    U[2]=U32(__floats2half2_rn( U01.x,U01.x)); U[3]=U32(__floats2half2_rn(-U01.y,U01.y));
    U[4]=U32(__floats2half2_rn( U10.x,U10.x)); U[5]=U32(__floats2half2_rn(-U10.y,U10.y));
    U[6]=U32(__floats2half2_rn( U11.x,U11.x)); U[7]=U32(__floats2half2_rn(-U11.y,U11.y));
  }
  if(tid < NQ){
    int q = tid;
    float ax = prm[q*3+0] + x[s*NQ+q];
    float ay = prm[q*3+1], az = prm[q*3+2];
    float cx,sx,cy,sy,cz,sz;
    sincosf(0.5f*ax,&sx,&cx); sincosf(0.5f*ay,&sy,&cy); sincosf(0.5f*az,&sz,&cz);
    l0c[q][0] = cmul2(make_float2(cz,-sz), make_float2(cy*cx,  sy*sx));   // U00
    l0c[q][1] = cmul2(make_float2(cz, sz), make_float2(sy*cx, -cy*sx));   // U10
  }
  __syncthreads();

  unsigned* __restrict__ base = ws + (size_t)s*NST;
  cg::grid_group grid = cg::this_grid();

  // ---- phase A: init product state in regs, 10 layer-1 gates, scatter to global ----
  {
    unsigned s0t = coset_base<0>(tid, piece);
    // shared product over qubits untouched by the 4 reg gens
    float2 P0 = make_float2(1.f, 0.f);
#pragma unroll
    for(int q=0;q<NQ;++q){
      if(!((TMA>>(13-q))&1)) P0 = cmul2(P0, l0c[q][(s0t>>(13-q))&1]);
    }
    __half2 a[16];
#pragma unroll
    for(int j=0;j<16;++j){
      unsigned pj = s0t ^ CJ0.v[j];
      float2 v = P0;
#pragma unroll
      for(int q=0;q<NQ;++q){
        if((TMA>>(13-q))&1) v = cmul2(v, l0c[q][(pj>>(13-q))&1]);
      }
      a[j] = __floats2half2_rn(v.x, v.y);
    }
    gates_of_phase<0>(a, Utab, s0t, lane);
#pragma unroll
    for(int j=0;j<16;++j) base[s0t ^ CJ0.v[j]] = U32(a[j]);
  }
  grid.sync();

  // ---- phase B: gather, 10 gates, scatter ----
  {
    unsigned s0t = coset_base<1>(tid, piece);
    __half2 a[16];
#pragma unroll
    for(int j=0;j<16;++j) a[j] = H2(base[s0t ^ CJ1.v[j]]);
    gates_of_phase<1>(a, Utab, s0t, lane);
#pragma unroll
    for(int j=0;j<16;++j) base[s0t ^ CJ1.v[j]] = U32(a[j]);
  }
  grid.sync();

  // ---- phase C: gather, 8 gates, expectations ----
  {
    unsigned s0t = coset_base<2>(tid, piece);
    __half2 a[16];
#pragma unroll
    for(int j=0;j<16;++j) a[j] = H2(base[s0t ^ CJ2.v[j]]);
    gates_of_phase<2>(a, Utab, s0t, lane);

    // 4-bit Walsh-Hadamard on |a|^2 (f32)
    float p[16];
#pragma unroll
    for(int j=0;j<16;++j){
      float re = __low2float(a[j]), im = __high2float(a[j]);
      p[j] = fmaf(re, re, im*im);
    }
#pragma unroll
    for(int bstep=1; bstep<16; bstep<<=1){
#pragma unroll
      for(int j=0;j<16;++j){
        if(!(j & bstep)){
          float u = p[j], v = p[j|bstep];
          p[j] = u + v;
          p[j|bstep] = u - v;
        }
      }
    }
    const int wave = tid >> 6;
#pragma unroll
    for(int w=0;w<NQ;++w){
      float v = (__builtin_popcount(M3.row[NQ-1-w] & s0t)&1) ? -p[SL.EJ4[w]] : p[SL.EJ4[w]];
      v = xsum64(v, lane);
      if(lane==0) red[wave][w]=v;
    }
    __syncthreads();
    if(tid < NQ){
      float t=0.f;
#pragma unroll
      for(int wv=0; wv<NWAVES; ++wv) t += red[wv][tid];
      atomicAdd(&out[s*NQ + tid], t);
    }
  }
}

}  // namespace

extern "C" void kernel_launch(void* const* d_in, const int* in_sizes, int n_in,
                              void* d_out, int out_size, void* d_ws, size_t ws_size,
                              hipStream_t stream) {
  const float* x   = (const float*)d_in[0];   // (batch, 14) f32
  const float* prm = (const float*)d_in[1];   // (3, 14, 3) f32
  float* out = (float*)d_out;                 // (batch, 14) f32
  int batch = in_sizes[0] / NQ;
  unsigned* ws = (unsigned*)d_ws;             // state: batch x 16384 u32 (f16x2) = 8 MB

  hipMemsetAsync(d_out, 0, (size_t)out_size*sizeof(float), stream);
  void* args[] = { (void*)&x, (void*)&prm, (void*)&ws, (void*)&out, (void*)&batch };
  hipLaunchCooperativeKernel((const void*)qsim_kernel, dim3(2*batch), dim3(BLOCK),
                             args, 0, stream);
}

// Round 15
// 47.036 us; speedup vs baseline: 2.8327x; 2.8327x over previous
//
#include <hip/hip_runtime.h>
#include <hip/hip_fp16.h>

namespace {

constexpr int NQ     = 14;
constexpr int NST    = 1 << NQ;
constexpr int BLOCK  = 512;
constexpr int NWAVES = BLOCK / 64;

// ---------------- compile-time GF(2) machinery (verified R9/R14 passing builds) ----------------
constexpr unsigned cparity(unsigned x){ x^=x>>8; x^=x>>4; x^=x>>2; x^=x>>1; return x&1u; }

struct Mat { unsigned row[NQ]; unsigned col[NQ]; };

constexpr Mat m_after(int nr){
  Mat m{};
  for(int p=0;p<NQ;++p){ m.row[p]=1u<<p; m.col[p]=1u<<p; }
  for(int l=0;l<nr;++l)
    for(int q=0;q<NQ;++q){
      int cq=(q==NQ-1)?NQ-1:q, tq=(q==NQ-1)?0:q+1;
      int Pc=NQ-1-cq, Pt=NQ-1-tq;
      m.row[Pt]^=m.row[Pc]; m.col[Pc]^=m.col[Pt];
    }
  return m;
}

constexpr Mat M1=m_after(1), M2=m_after(2), M3=m_after(3);
constexpr unsigned amask(int q){ return M1.col[NQ-1-q]; }
constexpr unsigned arow (int q){ return M1.row[NQ-1-q]; }
constexpr unsigned bmask(int q){ return M2.col[NQ-1-q]; }
constexpr unsigned brow (int q){ return M2.row[NQ-1-q]; }

constexpr int rank_of(const unsigned* v, int n){
  unsigned a[24]{};
  for(int i=0;i<n;++i) a[i]=v[i];
  int r=0;
  for(int bit=15;bit>=0;--bit){
    int p=-1;
    for(int i=r;i<n;++i){ if((a[i]>>bit)&1){ p=i; break; } }
    if(p<0) continue;
    unsigned t=a[r]; a[r]=a[p]; a[p]=t;
    for(int i=0;i<n;++i) if(i!=r && ((a[i]>>bit)&1)) a[i]^=a[r];
    ++r;
  }
  return r;
}

// ---- per-phase gate sets: K0 = L1 q0..9; K1 = L1 q10..13 + 6 L2; K2 = 8 L2 ----
struct Sel {
  int picked[6], wq[4], un[4];
  unsigned Gen[3][10];
  unsigned Row[3][10];
  unsigned BlanePi4[6];
  unsigned EJ4[NQ];
  int lq[3][10][2];
};

constexpr Sel make_sel(){
  Sel S{};
  unsigned cur[24]{}; int nc=0;
  for(int t=0;t<4;++t) cur[nc++]=amask(10+t);
  bool used[14]{}; int picked[14]{}; int np=0;
  for(int q=0;q<14 && np<10;++q){
    cur[nc]=bmask(q);
    if(rank_of(cur,nc+1)==nc+1){ ++nc; picked[np++]=q; used[q]=true; }
  }
  for(int i=0;i<6;++i) S.picked[i]=picked[i];
  for(int i=0;i<4;++i) S.wq[i]=picked[6+i];
  { int nu=0; for(int q=0;q<14;++q) if(!used[q]) S.un[nu++]=q; }
  for(int i=0;i<6;++i){ unsigned m=0;
    for(int t=0;t<4;++t) m |= cparity(brow(picked[i]) & amask(10+t))<<t;
    S.BlanePi4[i]=m; }
  for(int g=0;g<10;++g){ S.Gen[0][g]=amask(g);    S.Row[0][g]=arow(g);    S.lq[0][g][0]=1; S.lq[0][g][1]=g; }
  for(int g=0;g<4;++g) { S.Gen[1][g]=amask(10+g); S.Row[1][g]=arow(10+g); S.lq[1][g][0]=1; S.lq[1][g][1]=10+g; }
  for(int g=0;g<6;++g) { S.Gen[1][4+g]=bmask(picked[g]); S.Row[1][4+g]=brow(picked[g]);
                         S.lq[1][4+g][0]=2; S.lq[1][4+g][1]=picked[g]; }
  for(int g=0;g<4;++g) { S.Gen[2][g]=bmask(S.wq[g]); S.Row[2][g]=brow(S.wq[g]);
                         S.lq[2][g][0]=2; S.lq[2][g][1]=S.wq[g]; }
  for(int g=0;g<4;++g) { S.Gen[2][4+g]=bmask(S.un[g]); S.Row[2][4+g]=brow(S.un[g]);
                         S.lq[2][4+g][0]=2; S.lq[2][4+g][1]=S.un[g]; }
  { unsigned cc[24]{}; int n=0;
    for(int t=0;t<8;++t) cc[n++]=S.Gen[2][t];
    int pos=8;
    for(int p=0;p<14 && pos<10;++p){
      cc[n]=1u<<p;
      if(rank_of(cc,n+1)==n+1){ S.Gen[2][pos]=1u<<p; S.Row[2][pos]=0; ++n; ++pos; }
    } }
  for(int w=0;w<NQ;++w){
    unsigned R=M3.row[NQ-1-w]; unsigned mj=0;
    for(int t=0;t<4;++t) mj |= cparity(R & S.Gen[2][t])<<t;
    S.EJ4[w]=mj;
  }
  return S;
}
constexpr Sel SL = make_sel();
static_assert(rank_of(SL.Gen[0],10)==10, "K0 gens");
static_assert(rank_of(SL.Gen[1],10)==10, "K1 gens");
static_assert(rank_of(SL.Gen[2],10)==10, "K2 gens");

struct Ins { unsigned ins[10]; };
constexpr Ins make_ins(const unsigned* gen){
  unsigned a[10]{}; for(int i=0;i<10;++i) a[i]=gen[i];
  int piv[10]{}; int r=0;
  for(int bit=13;bit>=0;--bit){
    int p=-1;
    for(int i=r;i<10;++i){ if((a[i]>>bit)&1){ p=i; break; } }
    if(p<0) continue;
    unsigned t=a[r]; a[r]=a[p]; a[p]=t;
    for(int i=0;i<10;++i) if(i!=r && ((a[i]>>bit)&1)) a[i]^=a[r];
    piv[r++]=bit;
  }
  for(int i=0;i<10;++i) for(int j=i+1;j<10;++j)
    if(piv[j]<piv[i]){ int t=piv[i]; piv[i]=piv[j]; piv[j]=t; }
  Ins I{};
  for(int g=0;g<10;++g) I.ins[g]=(1u<<piv[g])-1u;
  return I;
}
constexpr Ins INS0=make_ins(SL.Gen[0]), INS1=make_ins(SL.Gen[1]), INS2=make_ins(SL.Gen[2]);

struct CJ16 { unsigned v[16]; };
constexpr CJ16 make_cj(const unsigned* gen){
  CJ16 c{};
  for(int j=0;j<16;++j){ unsigned s=0; for(int b=0;b<4;++b) if((j>>b)&1) s^=gen[b]; c.v[j]=s; }
  return c;
}
constexpr CJ16 CJ0=make_cj(SL.Gen[0]), CJ1=make_cj(SL.Gen[1]), CJ2=make_cj(SL.Gen[2]);

constexpr int gidx(int PH, int g){ return (SL.lq[PH][g][0]-1)*NQ + SL.lq[PH][g][1]; }
constexpr unsigned TMA = SL.Gen[0][0]|SL.Gen[0][1]|SL.Gen[0][2]|SL.Gen[0][3];

// ---- per-phase storage bases + transitions (NEW; mirrors R5/R7-verified trans machinery) ----
// coord packing: bits[0..3]=j (Gen[0..3]), [4..9]=tid0..5 (Gen[4..9]),
//                [10..12]=tid6..8 (rep(e0..2)), [13]=piece (rep(e3))
struct Basis { unsigned v[NQ]; };
constexpr unsigned rep_of(const Ins& I, unsigned e){
  unsigned r=e;
  for(int g=0;g<10;++g) r = ((r & ~I.ins[g])<<1) | (r & I.ins[g]);
  return r;
}
constexpr Basis make_basis(int PH){
  Basis B{};
  Ins I = (PH==0)?INS0:(PH==1)?INS1:INS2;
  for(int k=0;k<10;++k) B.v[k]=SL.Gen[PH][k];
  for(int k=0;k<4;++k)  B.v[10+k]=rep_of(I,1u<<k);
  return B;
}
constexpr Basis B0=make_basis(0), B1=make_basis(1), B2=make_basis(2);
static_assert(rank_of(B0.v,NQ)==NQ, "B0");
static_assert(rank_of(B1.v,NQ)==NQ, "B1");
static_assert(rank_of(B2.v,NQ)==NQ, "B2");

struct Inv { unsigned col[NQ]; };
constexpr Inv inv_basis(const unsigned* bas){
  unsigned vec[NQ]{}, cmb[NQ]{}; bool used[NQ]{}; int pivk[NQ]{};
  for(int k=0;k<NQ;++k){ vec[k]=bas[k]; cmb[k]=1u<<k; }
  for(int b=0;b<NQ;++b){
    int p=-1;
    for(int k=0;k<NQ;++k) if(!used[k] && ((vec[k]>>b)&1)){ p=k; break; }
    used[p]=true; pivk[b]=p;
    for(int k=0;k<NQ;++k) if(k!=p && ((vec[k]>>b)&1)){ vec[k]^=vec[p]; cmb[k]^=cmb[p]; }
  }
  Inv R{};
  for(int b=0;b<NQ;++b) R.col[b]=cmb[pivk[b]];
  return R;
}
constexpr bool check_inv(const unsigned* bas, const Inv& iv){
  for(int p=0;p<NQ;++p){
    unsigned s=0;
    for(int k=0;k<NQ;++k) if((iv.col[p]>>k)&1) s^=bas[k];
    if(s != (1u<<p)) return false;
  }
  return true;
}
constexpr Inv IB1 = inv_basis(B1.v), IB2 = inv_basis(B2.v);
static_assert(check_inv(B1.v, IB1), "IB1");
static_assert(check_inv(B2.v, IB2), "IB2");

struct Trans { unsigned t[NQ]; };
constexpr Trans trans_of(const unsigned* cur, const Inv& iv){
  Trans T{};
  for(int k=0;k<NQ;++k){
    unsigned c=0;
    for(int p=0;p<NQ;++p) if((cur[k]>>p)&1) c^=iv.col[p];
    T.t[k]=c;
  }
  return T;
}
constexpr Trans T01 = trans_of(B0.v, IB1);
constexpr Trans T12 = trans_of(B1.v, IB2);
// round-trip verification: image coords reconstruct the writer basis vector
constexpr bool check_trans(const Basis& W, const Basis& R, const Trans& T){
  for(int k=0;k<NQ;++k){
    unsigned s=0;
    for(int p=0;p<NQ;++p) if((T.t[k]>>p)&1) s^=R.v[p];
    if(s != W.v[k]) return false;
  }
  return true;
}
static_assert(check_trans(B0,B1,T01), "T01");
static_assert(check_trans(B1,B2,T12), "T12");
constexpr CJ16 CJW0 = make_cj(T01.t);   // writer K0: j-bit slot images
constexpr CJ16 CJW1 = make_cj(T12.t);

// ---------------- packed-f16 complex helpers (verified R13/R14 passing builds) ----------------
__device__ __forceinline__ __half2 H2(unsigned u){ return __builtin_bit_cast(__half2, u); }
__device__ __forceinline__ unsigned U32(__half2 h){ return __builtin_bit_cast(unsigned, h); }
__device__ __forceinline__ unsigned hswap(unsigned u){ return __builtin_amdgcn_alignbit(u, u, 16); }

__device__ __forceinline__ float2 cmul2(float2 a, float2 b){
  return make_float2(fmaf(a.x, b.x, -(a.y * b.y)),
                     fmaf(a.x, b.y,  a.y * b.x));
}

struct GC { unsigned e[8]; };
__device__ __forceinline__ GC load_gc(const unsigned* __restrict__ g){
  const uint4* p = reinterpret_cast<const uint4*>(g);
  uint4 q0=p[0], q1=p[1];
  GC c;
  c.e[0]=q0.x; c.e[1]=q0.y; c.e[2]=q0.z; c.e[3]=q0.w;
  c.e[4]=q1.x; c.e[5]=q1.y; c.e[6]=q1.z; c.e[7]=q1.w;
  return c;
}

__device__ __forceinline__ void gpair(__half2& r0, __half2& r1, const unsigned (&m)[8],
                                      __half2 a0, __half2 a1){
  __half2 a0s = H2(hswap(U32(a0))), a1s = H2(hswap(U32(a1)));
  r0 = __hfma2(H2(m[0]),a0, __hfma2(H2(m[1]),a0s, __hfma2(H2(m[2]),a1, __hmul2(H2(m[3]),a1s))));
  r1 = __hfma2(H2(m[4]),a0, __hfma2(H2(m[5]),a0s, __hfma2(H2(m[6]),a1, __hmul2(H2(m[7]),a1s))));
}

template<int CTRL>
__device__ __forceinline__ unsigned dppu(unsigned x){
  return (unsigned)__builtin_amdgcn_update_dpp(0, (int)x, CTRL, 0xF, 0xF, true);
}
__device__ __forceinline__ unsigned x32u(unsigned x, unsigned lane){
  auto r = __builtin_amdgcn_permlane32_swap(x, x, false, false);
  return (lane & 32u) ? (unsigned)r[0] : (unsigned)r[1];
}
__device__ __forceinline__ unsigned x16u(unsigned x, unsigned lane){
#if __has_builtin(__builtin_amdgcn_permlane16_swap)
  auto r = __builtin_amdgcn_permlane16_swap(x, x, false, false);
  return (lane & 16u) ? (unsigned)r[0] : (unsigned)r[1];
#else
  return (unsigned)__builtin_amdgcn_ds_swizzle((int)x, 0x401F);
#endif
}
template<int K>
__device__ __forceinline__ unsigned xpart_u32(unsigned x, unsigned lane){
  if constexpr (K==0) return dppu<0xB1>(x);
  else if constexpr (K==1) return dppu<0x4E>(x);
  else if constexpr (K==2) return (unsigned)__builtin_amdgcn_ds_swizzle((int)x,0x101F);
  else if constexpr (K==3) return dppu<0x128>(x);
  else if constexpr (K==4) return x16u(x,lane);
  else return x32u(x,lane);
}

template<int BIT>
__device__ __forceinline__ void reg_gate(__half2 (&a)[16], const GC& c, bool eps){
  unsigned m[8];
#pragma unroll
  for(int i=0;i<8;++i) m[i] = eps ? c.e[i^6] : c.e[i];
#pragma unroll
  for(int v=0; v<16; ++v){
    if(!((v>>BIT)&1)){
      int w = v | (1<<BIT);
      __half2 n0, n1;
      gpair(n0, n1, m, a[v], a[w]);
      a[v]=n0; a[w]=n1;
    }
  }
}

template<int XK, unsigned PI4>
__device__ __forceinline__ void lane_gate(__half2 (&a)[16], const GC& c, bool sel, unsigned lane){
  unsigned ka0x = sel?c.e[6]:c.e[0], ka0n = sel?c.e[7]:c.e[1];
  unsigned kb0x = sel?c.e[4]:c.e[2], kb0n = sel?c.e[5]:c.e[3];
  unsigned ka1x = sel?c.e[0]:c.e[6], ka1n = sel?c.e[1]:c.e[7];
  unsigned kb1x = sel?c.e[2]:c.e[4], kb1n = sel?c.e[3]:c.e[5];
  unsigned th[16];
#pragma unroll
  for(int j=0;j<16;++j) th[j] = xpart_u32<XK>(U32(a[j]), lane);
#pragma unroll
  for(int j=0;j<16;++j){
    bool pi = (__builtin_popcount(PI4 & (unsigned)j) & 1) != 0;
    unsigned kax = pi?ka1x:ka0x, kan = pi?ka1n:ka0n;
    unsigned kbx = pi?kb1x:kb0x, kbn = pi?kb1n:kb0n;
    __half2 as  = H2(hswap(U32(a[j])));
    __half2 ths = H2(hswap(th[j]));
    a[j] = __hfma2(H2(kax),a[j], __hfma2(H2(kan),as, __hfma2(H2(kbx),H2(th[j]), __hmul2(H2(kbn),ths))));
  }
}

__device__ __forceinline__ float xsum64(float v, unsigned lane){
  v += __int_as_float((int)dppu<0xB1>((unsigned)__float_as_int(v)));
  v += __int_as_float((int)dppu<0x4E>((unsigned)__float_as_int(v)));
  v += __int_as_float(__builtin_amdgcn_ds_swizzle(__float_as_int(v),0x101F));
  v += __int_as_float((int)dppu<0x128>((unsigned)__float_as_int(v)));
  v += __int_as_float((int)x16u((unsigned)__float_as_int(v), lane));
  v += __int_as_float((int)x32u((unsigned)__float_as_int(v), lane));
  return v;
}

template<int PH>
__device__ __forceinline__ unsigned coset_base(unsigned tid, int piece){
  constexpr Ins INS = (PH==0)?INS0:(PH==1)?INS1:INS2;
  unsigned e = (tid>>6) | ((unsigned)piece<<3);
#pragma unroll
  for(int g=0; g<10; ++g) e = ((e & ~INS.ins[g])<<1) | (e & INS.ins[g]);
  unsigned s0t = e;
#pragma unroll
  for(int k=0;k<6;++k) s0t ^= SL.Gen[PH][4+k] & (0u - ((tid>>k)&1u));
  return s0t;
}

template<int PH>
__device__ __forceinline__ void gates_of_phase(__half2 (&a)[16], const unsigned* __restrict__ Ut,
                                               unsigned s0t, unsigned lane){
  reg_gate<0>(a, load_gc(Ut+gidx(PH,0)*8), (__builtin_popcount(SL.Row[PH][0]&s0t)&1)!=0);
  reg_gate<1>(a, load_gc(Ut+gidx(PH,1)*8), (__builtin_popcount(SL.Row[PH][1]&s0t)&1)!=0);
  reg_gate<2>(a, load_gc(Ut+gidx(PH,2)*8), (__builtin_popcount(SL.Row[PH][2]&s0t)&1)!=0);
  reg_gate<3>(a, load_gc(Ut+gidx(PH,3)*8), (__builtin_popcount(SL.Row[PH][3]&s0t)&1)!=0);
  if constexpr (PH==0){
    lane_gate<0,0u>(a, load_gc(Ut+gidx(0,4)*8), (__builtin_popcount(SL.Row[0][4]&s0t)&1)!=0, lane);
    lane_gate<1,0u>(a, load_gc(Ut+gidx(0,5)*8), (__builtin_popcount(SL.Row[0][5]&s0t)&1)!=0, lane);
    lane_gate<2,0u>(a, load_gc(Ut+gidx(0,6)*8), (__builtin_popcount(SL.Row[0][6]&s0t)&1)!=0, lane);
    lane_gate<3,0u>(a, load_gc(Ut+gidx(0,7)*8), (__builtin_popcount(SL.Row[0][7]&s0t)&1)!=0, lane);
    lane_gate<4,0u>(a, load_gc(Ut+gidx(0,8)*8), (__builtin_popcount(SL.Row[0][8]&s0t)&1)!=0, lane);
    lane_gate<5,0u>(a, load_gc(Ut+gidx(0,9)*8), (__builtin_popcount(SL.Row[0][9]&s0t)&1)!=0, lane);
  } else if constexpr (PH==1){
    lane_gate<0,SL.BlanePi4[0]>(a, load_gc(Ut+gidx(1,4)*8), (__builtin_popcount(SL.Row[1][4]&s0t)&1)!=0, lane);
    lane_gate<1,SL.BlanePi4[1]>(a, load_gc(Ut+gidx(1,5)*8), (__builtin_popcount(SL.Row[1][5]&s0t)&1)!=0, lane);
    lane_gate<2,SL.BlanePi4[2]>(a, load_gc(Ut+gidx(1,6)*8), (__builtin_popcount(SL.Row[1][6]&s0t)&1)!=0, lane);
    lane_gate<3,SL.BlanePi4[3]>(a, load_gc(Ut+gidx(1,7)*8), (__builtin_popcount(SL.Row[1][7]&s0t)&1)!=0, lane);
    lane_gate<4,SL.BlanePi4[4]>(a, load_gc(Ut+gidx(1,8)*8), (__builtin_popcount(SL.Row[1][8]&s0t)&1)!=0, lane);
    lane_gate<5,SL.BlanePi4[5]>(a, load_gc(Ut+gidx(1,9)*8), (__builtin_popcount(SL.Row[1][9]&s0t)&1)!=0, lane);
  } else {
    lane_gate<0,0u>(a, load_gc(Ut+gidx(2,4)*8), (__builtin_popcount(SL.Row[2][4]&s0t)&1)!=0, lane);
    lane_gate<1,0u>(a, load_gc(Ut+gidx(2,5)*8), (__builtin_popcount(SL.Row[2][5]&s0t)&1)!=0, lane);
    lane_gate<2,0u>(a, load_gc(Ut+gidx(2,6)*8), (__builtin_popcount(SL.Row[2][6]&s0t)&1)!=0, lane);
    lane_gate<3,0u>(a, load_gc(Ut+gidx(2,7)*8), (__builtin_popcount(SL.Row[2][7]&s0t)&1)!=0, lane);
  }
}

// scatter into NEXT phase's layout via transition matrix
template<int WPH>
__device__ __forceinline__ void scatter_g(unsigned* __restrict__ base, const __half2 (&a)[16],
                                          unsigned tid, int piece){
  constexpr Trans T  = (WPH==0)?T01:T12;
  constexpr CJ16  CW = (WPH==0)?CJW0:CJW1;
  unsigned nb=0;
#pragma unroll
  for(int k=0;k<9;++k) nb ^= T.t[4+k] & (0u-((tid>>k)&1u));
  if(piece) nb ^= T.t[13];
#pragma unroll
  for(int j=0;j<16;++j) base[nb ^ CW.v[j]] = U32(a[j]);
}

// ---------------- the 3 chained kernels ----------------
template<int PH>
__global__ __launch_bounds__(BLOCK) void qk(
    const float* __restrict__ x, const float* __restrict__ prm,
    unsigned* __restrict__ ws, float* __restrict__ out, int batch)
{
  __shared__ alignas(16) unsigned Utab[28*8];
  __shared__ float2 l0c[NQ][2];
  __shared__ float  red[NWAVES][NQ];

  const int bid = blockIdx.x;
  const int piece = (bid >= batch) ? 1 : 0;
  const int s = bid - piece*batch;
  const unsigned tid = threadIdx.x;
  const unsigned lane = tid & 63u;

  if(tid < 28){
    int t = tid;
    int l = 1 + t/NQ, q = t % NQ;
    float ax=prm[(l*NQ+q)*3+0], ay=prm[(l*NQ+q)*3+1], az=prm[(l*NQ+q)*3+2];
    float cx,sx,cy,sy,cz,sz;
    sincosf(0.5f*ax,&sx,&cx); sincosf(0.5f*ay,&sy,&cy); sincosf(0.5f*az,&sz,&cz);
    float2 M00=make_float2(cy*cx, sy*sx),  M01=make_float2(-sy*cx,-cy*sx);
    float2 M10=make_float2(sy*cx,-cy*sx),  M11=make_float2(cy*cx,-sy*sx);
    float2 ez =make_float2(cz,-sz), ezc=make_float2(cz,sz);
    float2 U00=cmul2(ez,M00), U01=cmul2(ez,M01), U10=cmul2(ezc,M10), U11=cmul2(ezc,M11);
    unsigned* U = &Utab[t*8];
    U[0]=U32(__floats2half2_rn( U00.x,U00.x)); U[1]=U32(__floats2half2_rn(-U00.y,U00.y));
    U[2]=U32(__floats2half2_rn( U01.x,U01.x)); U[3]=U32(__floats2half2_rn(-U01.y,U01.y));
    U[4]=U32(__floats2half2_rn( U10.x,U10.x)); U[5]=U32(__floats2half2_rn(-U10.y,U10.y));
    U[6]=U32(__floats2half2_rn( U11.x,U11.x)); U[7]=U32(__floats2half2_rn(-U11.y,U11.y));
  }
  if constexpr (PH==0){
    if(tid < NQ){
      int q = tid;
      float ax = prm[q*3+0] + x[s*NQ+q];
      float ay = prm[q*3+1], az = prm[q*3+2];
      float cx,sx,cy,sy,cz,sz;
      sincosf(0.5f*ax,&sx,&cx); sincosf(0.5f*ay,&sy,&cy); sincosf(0.5f*az,&sz,&cz);
      l0c[q][0] = cmul2(make_float2(cz,-sz), make_float2(cy*cx,  sy*sx));   // U00
      l0c[q][1] = cmul2(make_float2(cz, sz), make_float2(sy*cx, -cy*sx));   // U10
    }
  }
  __syncthreads();

  unsigned* __restrict__ base = ws + (size_t)s*NST;
  const unsigned s0t = coset_base<PH>(tid, piece);
  __half2 a[16];

  if constexpr (PH==0){
    // init product state at physical indices (verified R14)
    float2 P0 = make_float2(1.f, 0.f);
#pragma unroll
    for(int q=0;q<NQ;++q){
      if(!((TMA>>(13-q))&1)) P0 = cmul2(P0, l0c[q][(s0t>>(13-q))&1]);
    }
#pragma unroll
    for(int j=0;j<16;++j){
      unsigned pj = s0t ^ CJ0.v[j];
      float2 v = P0;
#pragma unroll
      for(int q=0;q<NQ;++q){
        if((TMA>>(13-q))&1) v = cmul2(v, l0c[q][(pj>>(13-q))&1]);
      }
      a[j] = __floats2half2_rn(v.x, v.y);
    }
  } else {
    // coalesced read: 4 consecutive uint4 per thread in own-phase layout
    const uint4* p = reinterpret_cast<const uint4*>(base + (((unsigned)piece<<13) | (tid<<4)));
    uint4 r0=p[0], r1=p[1], r2=p[2], r3=p[3];
    a[0]=H2(r0.x); a[1]=H2(r0.y); a[2]=H2(r0.z); a[3]=H2(r0.w);
    a[4]=H2(r1.x); a[5]=H2(r1.y); a[6]=H2(r1.z); a[7]=H2(r1.w);
    a[8]=H2(r2.x); a[9]=H2(r2.y); a[10]=H2(r2.z); a[11]=H2(r2.w);
    a[12]=H2(r3.x); a[13]=H2(r3.y); a[14]=H2(r3.z); a[15]=H2(r3.w);
  }

  gates_of_phase<PH>(a, Utab, s0t, lane);

  if constexpr (PH<2){
    scatter_g<PH>(base, a, tid, piece);
  } else {
    float p[16];
#pragma unroll
    for(int j=0;j<16;++j){
      float re = __low2float(a[j]), im = __high2float(a[j]);
      p[j] = fmaf(re, re, im*im);
    }
#pragma unroll
    for(int bstep=1; bstep<16; bstep<<=1){
#pragma unroll
      for(int j=0;j<16;++j){
        if(!(j & bstep)){
          float u = p[j], v = p[j|bstep];
          p[j] = u + v;
          p[j|bstep] = u - v;
        }
      }
    }
    const int wave = tid >> 6;
#pragma unroll
    for(int w=0;w<NQ;++w){
      float v = (__builtin_popcount(M3.row[NQ-1-w] & s0t)&1) ? -p[SL.EJ4[w]] : p[SL.EJ4[w]];
      v = xsum64(v, lane);
      if(lane==0) red[wave][w]=v;
    }
    __syncthreads();
    if(tid < NQ){
      float t=0.f;
#pragma unroll
      for(int wv=0; wv<NWAVES; ++wv) t += red[wv][tid];
      atomicAdd(&out[s*NQ + tid], t);
    }
  }
}

}  // namespace

extern "C" void kernel_launch(void* const* d_in, const int* in_sizes, int n_in,
                              void* d_out, int out_size, void* d_ws, size_t ws_size,
                              hipStream_t stream) {
  const float* x   = (const float*)d_in[0];   // (batch, 14) f32
  const float* prm = (const float*)d_in[1];   // (3, 14, 3) f32
  float* out = (float*)d_out;                 // (batch, 14) f32
  int batch = in_sizes[0] / NQ;
  unsigned* ws = (unsigned*)d_ws;             // state: batch x 16384 u32 (f16x2) = 8 MB

  hipMemsetAsync(d_out, 0, (size_t)out_size*sizeof(float), stream);
  qk<0><<<2*batch, BLOCK, 0, stream>>>(x, prm, ws, out, batch);
  qk<1><<<2*batch, BLOCK, 0, stream>>>(x, prm, ws, out, batch);
  qk<2><<<2*batch, BLOCK, 0, stream>>>(x, prm, ws, out, batch);
}

// Round 16
// 39.763 us; speedup vs baseline: 3.3508x; 1.1829x over previous
//
#include <hip/hip_runtime.h>
#include <hip/hip_fp16.h>

namespace {

constexpr int NQ      = 14;
constexpr int NSTATES = 1 << NQ;
constexpr int BLOCK   = 1024;
constexpr int NWAVES  = BLOCK / 64;

// ---------------- compile-time GF(2) machinery (verified R2-R13) ----------------
constexpr unsigned cparity(unsigned x){ x^=x>>8; x^=x>>4; x^=x>>2; x^=x>>1; return x&1u; }

struct Mat { unsigned row[NQ]; unsigned col[NQ]; };

constexpr Mat m_after(int nr){
  Mat m{};
  for(int p=0;p<NQ;++p){ m.row[p]=1u<<p; m.col[p]=1u<<p; }
  for(int l=0;l<nr;++l)
    for(int q=0;q<NQ;++q){
      int cq=(q==NQ-1)?NQ-1:q, tq=(q==NQ-1)?0:q+1;
      int Pc=NQ-1-cq, Pt=NQ-1-tq;
      m.row[Pt]^=m.row[Pc]; m.col[Pc]^=m.col[Pt];
    }
  return m;
}

constexpr Mat M1=m_after(1), M2=m_after(2), M3=m_after(3);
constexpr unsigned amask(int q){ return M1.col[NQ-1-q]; }
constexpr unsigned arow (int q){ return M1.row[NQ-1-q]; }
constexpr unsigned bmask(int q){ return M2.col[NQ-1-q]; }
constexpr unsigned brow (int q){ return M2.row[NQ-1-q]; }

constexpr int rank_of(const unsigned* v, int n){
  unsigned a[24]{};
  for(int i=0;i<n;++i) a[i]=v[i];
  int r=0;
  for(int bit=15;bit>=0;--bit){
    int p=-1;
    for(int i=r;i<n;++i){ if((a[i]>>bit)&1){ p=i; break; } }
    if(p<0) continue;
    unsigned t=a[r]; a[r]=a[p]; a[p]=t;
    for(int i=0;i<n;++i) if(i!=r && ((a[i]>>bit)&1)) a[i]^=a[r];
    ++r;
  }
  return r;
}

struct Plan {
  unsigned A[14], B[14], C[14];
  int BlaneGi[6]; unsigned BlanePi4[6];
  int BregGi[4];  unsigned BregEps[4];
  int CregGi[4];  unsigned CregEps[4];
  int ClaneGi[4]; unsigned ClaneEps[4];
  unsigned EJ4[14], ET[14];
};

constexpr Plan make_plan(){
  Plan P{};
  for(int t=0;t<14;++t) P.A[t]=amask(t);
  for(int t=0;t<4;++t){ P.B[t]=amask(10+t); P.BregGi[t]=10+t; }
  bool used[14]{}; int picked[14]{}; int np=0;
  {
    unsigned cur[20]{}; int nc=0;
    for(int t=0;t<4;++t) cur[nc++]=P.B[t];
    for(int q=0;q<14 && np<10;++q){
      cur[nc]=bmask(q);
      if(rank_of(cur,nc+1)==nc+1){ ++nc; picked[np++]=q; used[q]=true; }
    }
  }
  for(int i=0;i<6;++i){ P.B[4+i]=bmask(picked[i]); P.BlaneGi[i]=14+picked[i]; }
  int wq[4]{}, un[4]{}; int nu=0;
  for(int i=0;i<4;++i){ wq[i]=picked[6+i]; P.B[10+i]=bmask(wq[i]); P.CregGi[i]=14+wq[i]; }
  for(int q=0;q<14;++q) if(!used[q]) un[nu++]=q;
  for(int i=0;i<4;++i) P.ClaneGi[i]=14+un[i];
  for(int i=0;i<4;++i){ unsigned m=0;
    for(int t=0;t<10;++t) m |= cparity(arow(10+i)&P.B[4+t])<<t;
    P.BregEps[i]=m; }
  for(int i=0;i<6;++i){ unsigned m=0;
    for(int t=0;t<4;++t) m |= cparity(brow(picked[i])&P.B[t])<<t;
    P.BlanePi4[i]=m; }
  for(int t=0;t<4;++t) P.C[t]=bmask(wq[t]);
  for(int t=0;t<4;++t) P.C[4+t]=bmask(un[t]);
  {
    unsigned cc[20]{}; int n=0;
    for(int t=0;t<8;++t) cc[n++]=P.C[t];
    int pos=8;
    for(int p=0;p<14 && pos<14;++p){
      cc[n]=1u<<p;
      if(rank_of(cc,n+1)==n+1){ P.C[pos]=1u<<p; ++n; ++pos; }
    }
  }
  for(int i=0;i<4;++i){ unsigned m=0;
    for(int t=0;t<10;++t) m |= cparity(brow(wq[i])&P.C[4+t])<<t;
    P.CregEps[i]=m; }
  for(int i=0;i<4;++i){ unsigned m=0;
    for(int t=0;t<10;++t){ if(t==i) continue; m |= cparity(brow(un[i])&P.C[4+t])<<t; }
    P.ClaneEps[i]=m; }
  for(int w=0;w<14;++w){
    unsigned R=M3.row[NQ-1-w]; unsigned mj=0, mt=0;
    for(int t=0;t<4;++t)  mj |= cparity(R&P.C[t])<<t;
    for(int t=0;t<10;++t) mt |= cparity(R&P.C[4+t])<<t;
    P.EJ4[w]=mj; P.ET[w]=mt;
  }
  return P;
}

constexpr Plan PL = make_plan();
static_assert(rank_of(PL.A,14)==14, "phase A map not bijective");
static_assert(rank_of(PL.B,14)==14, "phase B map not bijective");
static_assert(rank_of(PL.C,14)==14, "phase C map not bijective");

struct Inv { unsigned col[NQ]; };
constexpr Inv inv_basis(const unsigned* bas){
  unsigned vec[NQ]{}, cmb[NQ]{}; bool used[NQ]{}; int pivk[NQ]{};
  for(int k=0;k<NQ;++k){ vec[k]=bas[k]; cmb[k]=1u<<k; }
  for(int b=0;b<NQ;++b){
    int p=-1;
    for(int k=0;k<NQ;++k) if(!used[k] && ((vec[k]>>b)&1)){ p=k; break; }
    used[p]=true; pivk[b]=p;
    for(int k=0;k<NQ;++k) if(k!=p && ((vec[k]>>b)&1)){ vec[k]^=vec[p]; cmb[k]^=cmb[p]; }
  }
  Inv R{};
  for(int b=0;b<NQ;++b) R.col[b]=cmb[pivk[b]];
  return R;
}
constexpr bool check_inv(const unsigned* bas, const Inv& iv){
  for(int p=0;p<NQ;++p){
    unsigned s=0;
    for(int k=0;k<NQ;++k) if((iv.col[p]>>k)&1) s^=bas[k];
    if(s != (1u<<p)) return false;
  }
  return true;
}
constexpr Inv IA = inv_basis(PL.A), IB = inv_basis(PL.B), IC = inv_basis(PL.C);
static_assert(check_inv(PL.A, IA), "IA");
static_assert(check_inv(PL.B, IB), "IB");
static_assert(check_inv(PL.C, IC), "IC");

struct Trans { unsigned t[NQ]; };
constexpr Trans trans_phys(const Inv& iv){
  Trans T{};
  for(int p=0;p<NQ;++p) T.t[p]=iv.col[p];
  return T;
}
constexpr Trans trans_of(const unsigned* cur, const Inv& iv){
  Trans T{};
  for(int k=0;k<NQ;++k){
    unsigned c=0;
    for(int p=0;p<NQ;++p) if((cur[k]>>p)&1) c^=iv.col[p];
    T.t[k]=c;
  }
  return T;
}
constexpr Trans T_PA = trans_phys(IA);
constexpr Trans T_AB = trans_of(PL.A, IB);
constexpr Trans T_BC = trans_of(PL.B, IC);

struct CJ { unsigned v[16]; };
constexpr CJ mk_cj(const Trans& T){
  CJ c{};
  for(int j=0;j<16;++j){
    unsigned s=0;
    for(int b=0;b<4;++b) if((j>>b)&1) s^=T.t[b];
    c.v[j]=s;
  }
  return c;
}
constexpr CJ CJ_PA=mk_cj(T_PA), CJ_AB=mk_cj(T_AB), CJ_BC=mk_cj(T_BC);

// ---------------- packed-f16 complex helpers (verified R13 passing build) ----------------
__device__ __forceinline__ __half2 H2(unsigned u){ return __builtin_bit_cast(__half2, u); }
__device__ __forceinline__ unsigned U32(__half2 h){ return __builtin_bit_cast(unsigned, h); }
__device__ __forceinline__ unsigned hswap(unsigned u){ return __builtin_amdgcn_alignbit(u, u, 16); }

__device__ __forceinline__ float2 cmul2(float2 a, float2 b){
  return make_float2(fmaf(a.x, b.x, -(a.y * b.y)),
                     fmaf(a.x, b.y,  a.y * b.x));
}

struct GC { unsigned e[8]; };
__device__ __forceinline__ GC load_gc(const unsigned* __restrict__ g){
  const uint4* p = reinterpret_cast<const uint4*>(g);
  uint4 q0=p[0], q1=p[1];
  GC c;
  c.e[0]=q0.x; c.e[1]=q0.y; c.e[2]=q0.z; c.e[3]=q0.w;
  c.e[4]=q1.x; c.e[5]=q1.y; c.e[6]=q1.z; c.e[7]=q1.w;
  return c;
}

__device__ __forceinline__ void gpair(__half2& r0, __half2& r1, const unsigned (&m)[8],
                                      __half2 a0, __half2 a1){
  __half2 a0s = H2(hswap(U32(a0))), a1s = H2(hswap(U32(a1)));
  r0 = __hfma2(H2(m[0]),a0, __hfma2(H2(m[1]),a0s, __hfma2(H2(m[2]),a1, __hmul2(H2(m[3]),a1s))));
  r1 = __hfma2(H2(m[4]),a0, __hfma2(H2(m[5]),a0s, __hfma2(H2(m[6]),a1, __hmul2(H2(m[7]),a1s))));
}

template<int CTRL>
__device__ __forceinline__ unsigned dppu(unsigned x){
  return (unsigned)__builtin_amdgcn_update_dpp(0, (int)x, CTRL, 0xF, 0xF, true);
}
__device__ __forceinline__ unsigned x32u(unsigned x, unsigned lane){
  auto r = __builtin_amdgcn_permlane32_swap(x, x, false, false);
  return (lane & 32u) ? (unsigned)r[0] : (unsigned)r[1];
}
__device__ __forceinline__ unsigned x16u(unsigned x, unsigned lane){
#if __has_builtin(__builtin_amdgcn_permlane16_swap)
  auto r = __builtin_amdgcn_permlane16_swap(x, x, false, false);
  return (lane & 16u) ? (unsigned)r[0] : (unsigned)r[1];
#else
  return (unsigned)__builtin_amdgcn_ds_swizzle((int)x, 0x401F);
#endif
}
// K: 0:^1 1:^2 2:^4 3:^8 4:^16 5:^32
template<int K>
__device__ __forceinline__ unsigned xpart_u32(unsigned x, unsigned lane){
  if constexpr (K==0) return dppu<0xB1>(x);
  else if constexpr (K==1) return dppu<0x4E>(x);
  else if constexpr (K==2) return (unsigned)__builtin_amdgcn_ds_swizzle((int)x,0x101F);
  else if constexpr (K==3) return dppu<0x128>(x);
  else if constexpr (K==4) return x16u(x,lane);
  else return x32u(x,lane);
}

template<int BIT>
__device__ __forceinline__ void reg_gate(__half2 (&a)[16], const GC& c, bool eps){
  unsigned m[8];
#pragma unroll
  for(int i=0;i<8;++i) m[i] = eps ? c.e[i^6] : c.e[i];
#pragma unroll
  for(int v=0; v<16; ++v){
    if(!((v>>BIT)&1)){
      int w = v | (1<<BIT);
      __half2 n0, n1;
      gpair(n0, n1, m, a[v], a[w]);
      a[v]=n0; a[w]=n1;
    }
  }
}

template<int XK, unsigned PI4>
__device__ __forceinline__ void lane_gate(__half2 (&a)[16], const GC& c, bool sel, unsigned lane){
  unsigned ka0x = sel?c.e[6]:c.e[0], ka0n = sel?c.e[7]:c.e[1];
  unsigned kb0x = sel?c.e[4]:c.e[2], kb0n = sel?c.e[5]:c.e[3];
  unsigned ka1x = sel?c.e[0]:c.e[6], ka1n = sel?c.e[1]:c.e[7];
  unsigned kb1x = sel?c.e[2]:c.e[4], kb1n = sel?c.e[3]:c.e[5];
  unsigned th[16];
#pragma unroll
  for(int j=0;j<16;++j) th[j] = xpart_u32<XK>(U32(a[j]), lane);
#pragma unroll
  for(int j=0;j<16;++j){
    bool pi = (__builtin_popcount(PI4 & (unsigned)j) & 1) != 0;
    unsigned kax = pi?ka1x:ka0x, kan = pi?ka1n:ka0n;
    unsigned kbx = pi?kb1x:kb0x, kbn = pi?kb1n:kb0n;
    __half2 as  = H2(hswap(U32(a[j])));
    __half2 ths = H2(hswap(th[j]));
    a[j] = __hfma2(H2(kax),a[j], __hfma2(H2(kan),as, __hfma2(H2(kbx),H2(th[j]), __hmul2(H2(kbn),ths))));
  }
}

__device__ __forceinline__ float xsum64(float v, unsigned lane){
  v += __int_as_float((int)dppu<0xB1>((unsigned)__float_as_int(v)));
  v += __int_as_float((int)dppu<0x4E>((unsigned)__float_as_int(v)));
  v += __int_as_float(__builtin_amdgcn_ds_swizzle(__float_as_int(v),0x101F));
  v += __int_as_float((int)dppu<0x128>((unsigned)__float_as_int(v)));
  v += __int_as_float((int)x16u((unsigned)__float_as_int(v), lane));
  v += __int_as_float((int)x32u((unsigned)__float_as_int(v), lane));
  return v;
}

__device__ __forceinline__ unsigned nb_of(unsigned tid, const unsigned (&t)[NQ]){
  unsigned s=0;
#pragma unroll
  for(int k=0;k<10;++k) s ^= t[4+k] & (0u-((tid>>k)&1u));
  return s;
}

__device__ __forceinline__ void scatter16(unsigned* __restrict__ st, const __half2 (&a)[16],
                                          unsigned nb, const CJ& cj){
#pragma unroll
  for(int j=0;j<16;++j){
    unsigned d = nb ^ cj.v[j];
    st[d + (d>>4)] = U32(a[j]);
  }
}

// vectorized contiguous gather: 16 consecutive u32 at tid*17 (64B, 4x b128)
__device__ __forceinline__ void gather16(const unsigned* __restrict__ st, __half2 (&a)[16],
                                         unsigned tid){
  const uint4* p = reinterpret_cast<const uint4*>(st + tid*17u);
  uint4 r0=p[0], r1=p[1], r2=p[2], r3=p[3];
  a[0]=H2(r0.x); a[1]=H2(r0.y); a[2]=H2(r0.z); a[3]=H2(r0.w);
  a[4]=H2(r1.x); a[5]=H2(r1.y); a[6]=H2(r1.z); a[7]=H2(r1.w);
  a[8]=H2(r2.x); a[9]=H2(r2.y); a[10]=H2(r2.z); a[11]=H2(r2.w);
  a[12]=H2(r3.x); a[13]=H2(r3.y); a[14]=H2(r3.z); a[15]=H2(r3.w);
}

// ---------------- kernel ----------------
__global__ __launch_bounds__(BLOCK, 4) void qsim_kernel(
    const float* __restrict__ x,
    const float* __restrict__ prm,
    float* __restrict__ out)
{
  // f16x2 state (68KB) + occupancy pad to force 1 block/CU (>80KB total LDS)
  __shared__ unsigned st[BLOCK*17 + 4096];       // 84 KiB
  __shared__ alignas(16) unsigned Utab[28*8];    // packed gate constants (layers 1,2)
  __shared__ float2 l0c[NQ][2];
  __shared__ float  red[NWAVES][NQ];

  const int b = blockIdx.x;
  const unsigned tid = threadIdx.x;
  const unsigned lane = tid & 63u;

  // keep the pad observable so the compiler can't shrink the LDS block
  if(tid == 0) st[BLOCK*17 + 4095] = 0u;

  // ---- gate table built in-kernel, packed f16 ----
  if(tid < 28){
    int t = tid;
    int l = 1 + t/NQ, q = t % NQ;
    float ax=prm[(l*NQ+q)*3+0], ay=prm[(l*NQ+q)*3+1], az=prm[(l*NQ+q)*3+2];
    float cx,sx,cy,sy,cz,sz;
    sincosf(0.5f*ax,&sx,&cx); sincosf(0.5f*ay,&sy,&cy); sincosf(0.5f*az,&sz,&cz);
    float2 M00=make_float2(cy*cx, sy*sx),  M01=make_float2(-sy*cx,-cy*sx);
    float2 M10=make_float2(sy*cx,-cy*sx),  M11=make_float2(cy*cx,-sy*sx);
    float2 ez =make_float2(cz,-sz), ezc=make_float2(cz,sz);
    float2 U00=cmul2(ez,M00), U01=cmul2(ez,M01), U10=cmul2(ezc,M10), U11=cmul2(ezc,M11);
    unsigned* U = &Utab[t*8];
    U[0]=U32(__floats2half2_rn( U00.x,U00.x)); U[1]=U32(__floats2half2_rn(-U00.y,U00.y));
    U[2]=U32(__floats2half2_rn( U01.x,U01.x)); U[3]=U32(__floats2half2_rn(-U01.y,U01.y));
    U[4]=U32(__floats2half2_rn( U10.x,U10.x)); U[5]=U32(__floats2half2_rn(-U10.y,U10.y));
    U[6]=U32(__floats2half2_rn( U11.x,U11.x)); U[7]=U32(__floats2half2_rn(-U11.y,U11.y));
  }
  // ---- layer-0 columns (x-dependent), f32 ----
  if(tid < NQ){
    int q = tid;
    float ax = prm[q*3+0] + x[b*NQ+q];
    float ay = prm[q*3+1], az = prm[q*3+2];
    float cx,sx,cy,sy,cz,sz;
    sincosf(0.5f*ax,&sx,&cx); sincosf(0.5f*ay,&sy,&cy); sincosf(0.5f*az,&sz,&cz);
    l0c[q][0] = cmul2(make_float2(cz,-sz), make_float2(cy*cx,  sy*sx));   // U00
    l0c[q][1] = cmul2(make_float2(cz, sz), make_float2(sy*cx, -cy*sx));   // U10
  }
  __syncthreads();

  // ---- init: product state (f32) packed once, scattered into phase-A layout ----
  {
    float2 p01 = cmul2(l0c[0][(tid>>9)&1],  l0c[1][(tid>>8)&1]);
    float2 p23 = cmul2(l0c[2][(tid>>7)&1],  l0c[3][(tid>>6)&1]);
    float2 p45 = cmul2(l0c[4][(tid>>5)&1],  l0c[5][(tid>>4)&1]);
    float2 p67 = cmul2(l0c[6][(tid>>3)&1],  l0c[7][(tid>>2)&1]);
    float2 p89 = cmul2(l0c[8][(tid>>1)&1],  l0c[9][tid&1]);
    float2 Pk  = cmul2(cmul2(cmul2(p01,p23), cmul2(p45,p67)), p89);
    float2 t2[2], t4[4];
    t2[0]=cmul2(Pk,l0c[10][0]); t2[1]=cmul2(Pk,l0c[10][1]);
#pragma unroll
    for(int i=0;i<2;++i){ t4[2*i]=cmul2(t2[i],l0c[11][0]); t4[2*i+1]=cmul2(t2[i],l0c[11][1]); }
    __half2 a[16];
#pragma unroll
    for(int j=0;j<16;++j){
      float2 v = cmul2(cmul2(t4[j>>2], l0c[12][(j>>1)&1]), l0c[13][j&1]);
      a[j] = __floats2half2_rn(v.x, v.y);
    }
    scatter16(st, a, nb_of(tid, T_PA.t), CJ_PA);
  }
  __syncthreads();

  // ---- phase A: 4 reg + 6 lane layer-1 gates ----
  {
    __half2 a[16];
    gather16(st, a, tid);
    reg_gate<0>(a, load_gc(Utab+0*8), false);
    reg_gate<1>(a, load_gc(Utab+1*8), false);
    reg_gate<2>(a, load_gc(Utab+2*8), false);
    reg_gate<3>(a, load_gc(Utab+3*8), false);
    lane_gate<0,0u>(a, load_gc(Utab+4*8), (tid&1)!=0,  lane);
    lane_gate<1,0u>(a, load_gc(Utab+5*8), (tid&2)!=0,  lane);
    lane_gate<2,0u>(a, load_gc(Utab+6*8), (tid&4)!=0,  lane);
    lane_gate<3,0u>(a, load_gc(Utab+7*8), (tid&8)!=0,  lane);
    lane_gate<4,0u>(a, load_gc(Utab+8*8), (tid&16)!=0, lane);
    lane_gate<5,0u>(a, load_gc(Utab+9*8), (tid&32)!=0, lane);
    __syncthreads();                      // all reads done before cross-layout writes
    scatter16(st, a, nb_of(tid, T_AB.t), CJ_AB);
  }
  __syncthreads();

  // ---- phase B: 4 leftover layer-1 reg gates (runtime eps) + 6 layer-2 lane gates ----
  {
    __half2 a[16];
    gather16(st, a, tid);
    reg_gate<0>(a, load_gc(Utab+PL.BregGi[0]*8), (__builtin_popcount(PL.BregEps[0]&tid)&1)!=0);
    reg_gate<1>(a, load_gc(Utab+PL.BregGi[1]*8), (__builtin_popcount(PL.BregEps[1]&tid)&1)!=0);
    reg_gate<2>(a, load_gc(Utab+PL.BregGi[2]*8), (__builtin_popcount(PL.BregEps[2]&tid)&1)!=0);
    reg_gate<3>(a, load_gc(Utab+PL.BregGi[3]*8), (__builtin_popcount(PL.BregEps[3]&tid)&1)!=0);
    lane_gate<0,PL.BlanePi4[0]>(a, load_gc(Utab+PL.BlaneGi[0]*8), (tid&1)!=0,  lane);
    lane_gate<1,PL.BlanePi4[1]>(a, load_gc(Utab+PL.BlaneGi[1]*8), (tid&2)!=0,  lane);
    lane_gate<2,PL.BlanePi4[2]>(a, load_gc(Utab+PL.BlaneGi[2]*8), (tid&4)!=0,  lane);
    lane_gate<3,PL.BlanePi4[3]>(a, load_gc(Utab+PL.BlaneGi[3]*8), (tid&8)!=0,  lane);
    lane_gate<4,PL.BlanePi4[4]>(a, load_gc(Utab+PL.BlaneGi[4]*8), (tid&16)!=0, lane);
    lane_gate<5,PL.BlanePi4[5]>(a, load_gc(Utab+PL.BlaneGi[5]*8), (tid&32)!=0, lane);
    __syncthreads();
    scatter16(st, a, nb_of(tid, T_BC.t), CJ_BC);
  }
  __syncthreads();

  // ---- phase C: last 8 layer-2 gates, expectation from registers ----
  {
    __half2 a[16];
    gather16(st, a, tid);
    reg_gate<0>(a, load_gc(Utab+PL.CregGi[0]*8), (__builtin_popcount(PL.CregEps[0]&tid)&1)!=0);
    reg_gate<1>(a, load_gc(Utab+PL.CregGi[1]*8), (__builtin_popcount(PL.CregEps[1]&tid)&1)!=0);
    reg_gate<2>(a, load_gc(Utab+PL.CregGi[2]*8), (__builtin_popcount(PL.CregEps[2]&tid)&1)!=0);
    reg_gate<3>(a, load_gc(Utab+PL.CregGi[3]*8), (__builtin_popcount(PL.CregEps[3]&tid)&1)!=0);
    lane_gate<0,0u>(a, load_gc(Utab+PL.ClaneGi[0]*8),
        (((tid&1u)!=0) != ((__builtin_popcount(PL.ClaneEps[0]&tid)&1)!=0)), lane);
    lane_gate<1,0u>(a, load_gc(Utab+PL.ClaneGi[1]*8),
        (((tid&2u)!=0) != ((__builtin_popcount(PL.ClaneEps[1]&tid)&1)!=0)), lane);
    lane_gate<2,0u>(a, load_gc(Utab+PL.ClaneGi[2]*8),
        (((tid&4u)!=0) != ((__builtin_popcount(PL.ClaneEps[2]&tid)&1)!=0)), lane);
    lane_gate<3,0u>(a, load_gc(Utab+PL.ClaneGi[3]*8),
        (((tid&8u)!=0) != ((__builtin_popcount(PL.ClaneEps[3]&tid)&1)!=0)), lane);

    // ---- expectation via 4-bit Walsh-Hadamard on |a|^2 (f32) ----
    float p[16];
#pragma unroll
    for(int j=0;j<16;++j){
      float re = __low2float(a[j]), im = __high2float(a[j]);
      p[j] = fmaf(re, re, im*im);
    }
#pragma unroll
    for(int bstep=1; bstep<16; bstep<<=1){
#pragma unroll
      for(int j=0;j<16;++j){
        if(!(j & bstep)){
          float u = p[j], v = p[j|bstep];
          p[j] = u + v;
          p[j|bstep] = u - v;
        }
      }
    }
    const int wave = tid >> 6;
#pragma unroll
    for(int w=0;w<NQ;++w){
      float v = (__builtin_popcount(PL.ET[w]&tid)&1) ? -p[PL.EJ4[w]] : p[PL.EJ4[w]];
      v = xsum64(v, lane);
      if(lane==0) red[wave][w]=v;
    }
    __syncthreads();
    if(tid < NQ){
      float s=0.f;
#pragma unroll
      for(int wv=0; wv<NWAVES; ++wv) s += red[wv][tid];
      out[b*NQ + tid] = s;
    }
  }
}

}  // namespace

extern "C" void kernel_launch(void* const* d_in, const int* in_sizes, int n_in,
                              void* d_out, int out_size, void* d_ws, size_t ws_size,
                              hipStream_t stream) {
  const float* x   = (const float*)d_in[0];   // (batch, 14) f32
  const float* prm = (const float*)d_in[1];   // (3, 14, 3) f32
  float* out = (float*)d_out;                 // (batch, 14) f32
  const int batch = in_sizes[0] / NQ;
  qsim_kernel<<<batch, BLOCK, 0, stream>>>(x, prm, out);
}

// Round 17
// 39.710 us; speedup vs baseline: 3.3553x; 1.0013x over previous
//
#include <hip/hip_runtime.h>
#include <hip/hip_fp16.h>

namespace {

constexpr int NQ      = 14;
constexpr int NSTATES = 1 << NQ;
constexpr int BLOCK   = 1024;
constexpr int NWAVES  = BLOCK / 64;

// ---------------- compile-time GF(2) machinery (verified R2-R16) ----------------
constexpr unsigned cparity(unsigned x){ x^=x>>8; x^=x>>4; x^=x>>2; x^=x>>1; return x&1u; }

struct Mat { unsigned row[NQ]; unsigned col[NQ]; };

constexpr Mat m_after(int nr){
  Mat m{};
  for(int p=0;p<NQ;++p){ m.row[p]=1u<<p; m.col[p]=1u<<p; }
  for(int l=0;l<nr;++l)
    for(int q=0;q<NQ;++q){
      int cq=(q==NQ-1)?NQ-1:q, tq=(q==NQ-1)?0:q+1;
      int Pc=NQ-1-cq, Pt=NQ-1-tq;
      m.row[Pt]^=m.row[Pc]; m.col[Pc]^=m.col[Pt];
    }
  return m;
}

constexpr Mat M1=m_after(1), M2=m_after(2), M3=m_after(3);
constexpr unsigned amask(int q){ return M1.col[NQ-1-q]; }
constexpr unsigned arow (int q){ return M1.row[NQ-1-q]; }
constexpr unsigned bmask(int q){ return M2.col[NQ-1-q]; }
constexpr unsigned brow (int q){ return M2.row[NQ-1-q]; }

constexpr int rank_of(const unsigned* v, int n){
  unsigned a[24]{};
  for(int i=0;i<n;++i) a[i]=v[i];
  int r=0;
  for(int bit=15;bit>=0;--bit){
    int p=-1;
    for(int i=r;i<n;++i){ if((a[i]>>bit)&1){ p=i; break; } }
    if(p<0) continue;
    unsigned t=a[r]; a[r]=a[p]; a[p]=t;
    for(int i=0;i<n;++i) if(i!=r && ((a[i]>>bit)&1)) a[i]^=a[r];
    ++r;
  }
  return r;
}

struct Plan {
  unsigned A[14], B[14], C[14];
  int BlaneGi[6]; unsigned BlanePi4[6];
  int BregGi[4];  unsigned BregEps[4];
  int CregGi[4];  unsigned CregEps[4];
  int ClaneGi[4]; unsigned ClaneEps[4];
  unsigned EJ4[14], ET[14];
};

constexpr Plan make_plan(){
  Plan P{};
  for(int t=0;t<14;++t) P.A[t]=amask(t);
  for(int t=0;t<4;++t){ P.B[t]=amask(10+t); P.BregGi[t]=10+t; }
  bool used[14]{}; int picked[14]{}; int np=0;
  {
    unsigned cur[20]{}; int nc=0;
    for(int t=0;t<4;++t) cur[nc++]=P.B[t];
    for(int q=0;q<14 && np<10;++q){
      cur[nc]=bmask(q);
      if(rank_of(cur,nc+1)==nc+1){ ++nc; picked[np++]=q; used[q]=true; }
    }
  }
  for(int i=0;i<6;++i){ P.B[4+i]=bmask(picked[i]); P.BlaneGi[i]=14+picked[i]; }
  int wq[4]{}, un[4]{}; int nu=0;
  for(int i=0;i<4;++i){ wq[i]=picked[6+i]; P.B[10+i]=bmask(wq[i]); P.CregGi[i]=14+wq[i]; }
  for(int q=0;q<14;++q) if(!used[q]) un[nu++]=q;
  for(int i=0;i<4;++i) P.ClaneGi[i]=14+un[i];
  for(int i=0;i<4;++i){ unsigned m=0;
    for(int t=0;t<10;++t) m |= cparity(arow(10+i)&P.B[4+t])<<t;
    P.BregEps[i]=m; }
  for(int i=0;i<6;++i){ unsigned m=0;
    for(int t=0;t<4;++t) m |= cparity(brow(picked[i])&P.B[t])<<t;
    P.BlanePi4[i]=m; }
  for(int t=0;t<4;++t) P.C[t]=bmask(wq[t]);
  for(int t=0;t<4;++t) P.C[4+t]=bmask(un[t]);
  {
    unsigned cc[20]{}; int n=0;
    for(int t=0;t<8;++t) cc[n++]=P.C[t];
    int pos=8;
    for(int p=0;p<14 && pos<14;++p){
      cc[n]=1u<<p;
      if(rank_of(cc,n+1)==n+1){ P.C[pos]=1u<<p; ++n; ++pos; }
    }
  }
  for(int i=0;i<4;++i){ unsigned m=0;
    for(int t=0;t<10;++t) m |= cparity(brow(wq[i])&P.C[4+t])<<t;
    P.CregEps[i]=m; }
  for(int i=0;i<4;++i){ unsigned m=0;
    for(int t=0;t<10;++t){ if(t==i) continue; m |= cparity(brow(un[i])&P.C[4+t])<<t; }
    P.ClaneEps[i]=m; }
  for(int w=0;w<14;++w){
    unsigned R=M3.row[NQ-1-w]; unsigned mj=0, mt=0;
    for(int t=0;t<4;++t)  mj |= cparity(R&P.C[t])<<t;
    for(int t=0;t<10;++t) mt |= cparity(R&P.C[4+t])<<t;
    P.EJ4[w]=mj; P.ET[w]=mt;
  }
  return P;
}

constexpr Plan PL = make_plan();
static_assert(rank_of(PL.A,14)==14, "phase A map not bijective");
static_assert(rank_of(PL.B,14)==14, "phase B map not bijective");
static_assert(rank_of(PL.C,14)==14, "phase C map not bijective");

struct Inv { unsigned col[NQ]; };
constexpr Inv inv_basis(const unsigned* bas){
  unsigned vec[NQ]{}, cmb[NQ]{}; bool used[NQ]{}; int pivk[NQ]{};
  for(int k=0;k<NQ;++k){ vec[k]=bas[k]; cmb[k]=1u<<k; }
  for(int b=0;b<NQ;++b){
    int p=-1;
    for(int k=0;k<NQ;++k) if(!used[k] && ((vec[k]>>b)&1)){ p=k; break; }
    used[p]=true; pivk[b]=p;
    for(int k=0;k<NQ;++k) if(k!=p && ((vec[k]>>b)&1)){ vec[k]^=vec[p]; cmb[k]^=cmb[p]; }
  }
  Inv R{};
  for(int b=0;b<NQ;++b) R.col[b]=cmb[pivk[b]];
  return R;
}
constexpr bool check_inv(const unsigned* bas, const Inv& iv){
  for(int p=0;p<NQ;++p){
    unsigned s=0;
    for(int k=0;k<NQ;++k) if((iv.col[p]>>k)&1) s^=bas[k];
    if(s != (1u<<p)) return false;
  }
  return true;
}
constexpr Inv IA = inv_basis(PL.A), IB = inv_basis(PL.B), IC = inv_basis(PL.C);
static_assert(check_inv(PL.A, IA), "IA");
static_assert(check_inv(PL.B, IB), "IB");
static_assert(check_inv(PL.C, IC), "IC");

struct Trans { unsigned t[NQ]; };
constexpr Trans trans_phys(const Inv& iv){
  Trans T{};
  for(int p=0;p<NQ;++p) T.t[p]=iv.col[p];
  return T;
}
constexpr Trans trans_of(const unsigned* cur, const Inv& iv){
  Trans T{};
  for(int k=0;k<NQ;++k){
    unsigned c=0;
    for(int p=0;p<NQ;++p) if((cur[k]>>p)&1) c^=iv.col[p];
    T.t[k]=c;
  }
  return T;
}
constexpr Trans T_PA = trans_phys(IA);
constexpr Trans T_AB = trans_of(PL.A, IB);
constexpr Trans T_BC = trans_of(PL.B, IC);

struct CJ { unsigned v[16]; };
constexpr CJ mk_cj(const Trans& T){
  CJ c{};
  for(int j=0;j<16;++j){
    unsigned s=0;
    for(int b=0;b<4;++b) if((j>>b)&1) s^=T.t[b];
    c.v[j]=s;
  }
  return c;
}
constexpr CJ CJ_PA=mk_cj(T_PA), CJ_AB=mk_cj(T_AB), CJ_BC=mk_cj(T_BC);

// ---------------- packed-f16 complex helpers (verified R13 passing build) ----------------
__device__ __forceinline__ __half2 H2(unsigned u){ return __builtin_bit_cast(__half2, u); }
__device__ __forceinline__ unsigned U32(__half2 h){ return __builtin_bit_cast(unsigned, h); }
__device__ __forceinline__ unsigned hswap(unsigned u){ return __builtin_amdgcn_alignbit(u, u, 16); }

__device__ __forceinline__ float2 cmul2(float2 a, float2 b){
  return make_float2(fmaf(a.x, b.x, -(a.y * b.y)),
                     fmaf(a.x, b.y,  a.y * b.x));
}

struct GC { unsigned e[8]; };
__device__ __forceinline__ GC load_gc(const unsigned* __restrict__ g){
  const uint4* p = reinterpret_cast<const uint4*>(g);
  uint4 q0=p[0], q1=p[1];
  GC c;
  c.e[0]=q0.x; c.e[1]=q0.y; c.e[2]=q0.z; c.e[3]=q0.w;
  c.e[4]=q1.x; c.e[5]=q1.y; c.e[6]=q1.z; c.e[7]=q1.w;
  return c;
}

__device__ __forceinline__ void gpair(__half2& r0, __half2& r1, const unsigned (&m)[8],
                                      __half2 a0, __half2 a1){
  __half2 a0s = H2(hswap(U32(a0))), a1s = H2(hswap(U32(a1)));
  r0 = __hfma2(H2(m[0]),a0, __hfma2(H2(m[1]),a0s, __hfma2(H2(m[2]),a1, __hmul2(H2(m[3]),a1s))));
  r1 = __hfma2(H2(m[4]),a0, __hfma2(H2(m[5]),a0s, __hfma2(H2(m[6]),a1, __hmul2(H2(m[7]),a1s))));
}

template<int CTRL>
__device__ __forceinline__ unsigned dppu(unsigned x){
  return (unsigned)__builtin_amdgcn_update_dpp(0, (int)x, CTRL, 0xF, 0xF, true);
}
__device__ __forceinline__ unsigned x32u(unsigned x, unsigned lane){
  auto r = __builtin_amdgcn_permlane32_swap(x, x, false, false);
  return (lane & 32u) ? (unsigned)r[0] : (unsigned)r[1];
}
__device__ __forceinline__ unsigned x16u(unsigned x, unsigned lane){
#if __has_builtin(__builtin_amdgcn_permlane16_swap)
  auto r = __builtin_amdgcn_permlane16_swap(x, x, false, false);
  return (lane & 16u) ? (unsigned)r[0] : (unsigned)r[1];
#else
  return (unsigned)__builtin_amdgcn_ds_swizzle((int)x, 0x401F);
#endif
}
// K: 0:^1 1:^2 2:^4 3:^8 4:^16 5:^32
template<int K>
__device__ __forceinline__ unsigned xpart_u32(unsigned x, unsigned lane){
  if constexpr (K==0) return dppu<0xB1>(x);
  else if constexpr (K==1) return dppu<0x4E>(x);
  else if constexpr (K==2) return (unsigned)__builtin_amdgcn_ds_swizzle((int)x,0x101F);
  else if constexpr (K==3) return dppu<0x128>(x);
  else if constexpr (K==4) return x16u(x,lane);
  else return x32u(x,lane);
}

template<int BIT>
__device__ __forceinline__ void reg_gate(__half2 (&a)[16], const GC& c, bool eps){
  unsigned m[8];
#pragma unroll
  for(int i=0;i<8;++i) m[i] = eps ? c.e[i^6] : c.e[i];
#pragma unroll
  for(int v=0; v<16; ++v){
    if(!((v>>BIT)&1)){
      int w = v | (1<<BIT);
      __half2 n0, n1;
      gpair(n0, n1, m, a[v], a[w]);
      a[v]=n0; a[w]=n1;
    }
  }
}

template<int XK, unsigned PI4>
__device__ __forceinline__ void lane_gate(__half2 (&a)[16], const GC& c, bool sel, unsigned lane){
  unsigned ka0x = sel?c.e[6]:c.e[0], ka0n = sel?c.e[7]:c.e[1];
  unsigned kb0x = sel?c.e[4]:c.e[2], kb0n = sel?c.e[5]:c.e[3];
  unsigned ka1x = sel?c.e[0]:c.e[6], ka1n = sel?c.e[1]:c.e[7];
  unsigned kb1x = sel?c.e[2]:c.e[4], kb1n = sel?c.e[3]:c.e[5];
  unsigned th[16];
#pragma unroll
  for(int j=0;j<16;++j) th[j] = xpart_u32<XK>(U32(a[j]), lane);
#pragma unroll
  for(int j=0;j<16;++j){
    bool pi = (__builtin_popcount(PI4 & (unsigned)j) & 1) != 0;
    unsigned kax = pi?ka1x:ka0x, kan = pi?ka1n:ka0n;
    unsigned kbx = pi?kb1x:kb0x, kbn = pi?kb1n:kb0n;
    __half2 as  = H2(hswap(U32(a[j])));
    __half2 ths = H2(hswap(th[j]));
    a[j] = __hfma2(H2(kax),a[j], __hfma2(H2(kan),as, __hfma2(H2(kbx),H2(th[j]), __hmul2(H2(kbn),ths))));
  }
}

__device__ __forceinline__ float xsum64(float v, unsigned lane){
  v += __int_as_float((int)dppu<0xB1>((unsigned)__float_as_int(v)));
  v += __int_as_float((int)dppu<0x4E>((unsigned)__float_as_int(v)));
  v += __int_as_float(__builtin_amdgcn_ds_swizzle(__float_as_int(v),0x101F));
  v += __int_as_float((int)dppu<0x128>((unsigned)__float_as_int(v)));
  v += __int_as_float((int)x16u((unsigned)__float_as_int(v), lane));
  v += __int_as_float((int)x32u((unsigned)__float_as_int(v), lane));
  return v;
}

__device__ __forceinline__ unsigned nb_of(unsigned tid, const unsigned (&t)[NQ]){
  unsigned s=0;
#pragma unroll
  for(int k=0;k<10;++k) s ^= t[4+k] & (0u-((tid>>k)&1u));
  return s;
}

__device__ __forceinline__ void scatter16(unsigned* __restrict__ st, const __half2 (&a)[16],
                                          unsigned nb, const CJ& cj){
#pragma unroll
  for(int j=0;j<16;++j){
    unsigned d = nb ^ cj.v[j];
    st[d + (d>>4)] = U32(a[j]);
  }
}

// vectorized contiguous gather: 16 consecutive u32 at tid*17 (64B, 4x b128)
__device__ __forceinline__ void gather16(const unsigned* __restrict__ st, __half2 (&a)[16],
                                         unsigned tid){
  const uint4* p = reinterpret_cast<const uint4*>(st + tid*17u);
  uint4 r0=p[0], r1=p[1], r2=p[2], r3=p[3];
  a[0]=H2(r0.x); a[1]=H2(r0.y); a[2]=H2(r0.z); a[3]=H2(r0.w);
  a[4]=H2(r1.x); a[5]=H2(r1.y); a[6]=H2(r1.z); a[7]=H2(r1.w);
  a[8]=H2(r2.x); a[9]=H2(r2.y); a[10]=H2(r2.z); a[11]=H2(r2.w);
  a[12]=H2(r3.x); a[13]=H2(r3.y); a[14]=H2(r3.z); a[15]=H2(r3.w);
}

// ---------------- kernel ----------------
__global__ __launch_bounds__(BLOCK, 4) void qsim_kernel(
    const float* __restrict__ x,
    const float* __restrict__ prm,
    float* __restrict__ out)
{
  __shared__ unsigned st[BLOCK*17];              // f16x2 state, 4B pad/thread (68 KiB)
  __shared__ alignas(16) unsigned Utab[28*8];    // packed gate constants (layers 1,2)
  __shared__ float2 l0c[NQ][2];
  __shared__ float  red[NWAVES][NQ];

  const int b = blockIdx.x;
  const unsigned tid = threadIdx.x;
  const unsigned lane = tid & 63u;

  // ---- gate table built in-kernel, packed f16 ----
  if(tid < 28){
    int t = tid;
    int l = 1 + t/NQ, q = t % NQ;
    float ax=prm[(l*NQ+q)*3+0], ay=prm[(l*NQ+q)*3+1], az=prm[(l*NQ+q)*3+2];
    float cx,sx,cy,sy,cz,sz;
    sincosf(0.5f*ax,&sx,&cx); sincosf(0.5f*ay,&sy,&cy); sincosf(0.5f*az,&sz,&cz);
    float2 M00=make_float2(cy*cx, sy*sx),  M01=make_float2(-sy*cx,-cy*sx);
    float2 M10=make_float2(sy*cx,-cy*sx),  M11=make_float2(cy*cx,-sy*sx);
    float2 ez =make_float2(cz,-sz), ezc=make_float2(cz,sz);
    float2 U00=cmul2(ez,M00), U01=cmul2(ez,M01), U10=cmul2(ezc,M10), U11=cmul2(ezc,M11);
    unsigned* U = &Utab[t*8];
    U[0]=U32(__floats2half2_rn( U00.x,U00.x)); U[1]=U32(__floats2half2_rn(-U00.y,U00.y));
    U[2]=U32(__floats2half2_rn( U01.x,U01.x)); U[3]=U32(__floats2half2_rn(-U01.y,U01.y));
    U[4]=U32(__floats2half2_rn( U10.x,U10.x)); U[5]=U32(__floats2half2_rn(-U10.y,U10.y));
    U[6]=U32(__floats2half2_rn( U11.x,U11.x)); U[7]=U32(__floats2half2_rn(-U11.y,U11.y));
  }
  // ---- layer-0 columns (x-dependent), f32 ----
  if(tid < NQ){
    int q = tid;
    float ax = prm[q*3+0] + x[b*NQ+q];
    float ay = prm[q*3+1], az = prm[q*3+2];
    float cx,sx,cy,sy,cz,sz;
    sincosf(0.5f*ax,&sx,&cx); sincosf(0.5f*ay,&sy,&cy); sincosf(0.5f*az,&sz,&cz);
    l0c[q][0] = cmul2(make_float2(cz,-sz), make_float2(cy*cx,  sy*sx));   // U00
    l0c[q][1] = cmul2(make_float2(cz, sz), make_float2(sy*cx, -cy*sx));   // U10
  }
  __syncthreads();

  // ---- init: product state (f32) packed once, scattered into phase-A layout ----
  {
    float2 p01 = cmul2(l0c[0][(tid>>9)&1],  l0c[1][(tid>>8)&1]);
    float2 p23 = cmul2(l0c[2][(tid>>7)&1],  l0c[3][(tid>>6)&1]);
    float2 p45 = cmul2(l0c[4][(tid>>5)&1],  l0c[5][(tid>>4)&1]);
    float2 p67 = cmul2(l0c[6][(tid>>3)&1],  l0c[7][(tid>>2)&1]);
    float2 p89 = cmul2(l0c[8][(tid>>1)&1],  l0c[9][tid&1]);
    float2 Pk  = cmul2(cmul2(cmul2(p01,p23), cmul2(p45,p67)), p89);
    float2 t2[2], t4[4];
    t2[0]=cmul2(Pk,l0c[10][0]); t2[1]=cmul2(Pk,l0c[10][1]);
#pragma unroll
    for(int i=0;i<2;++i){ t4[2*i]=cmul2(t2[i],l0c[11][0]); t4[2*i+1]=cmul2(t2[i],l0c[11][1]); }
    __half2 a[16];
#pragma unroll
    for(int j=0;j<16;++j){
      float2 v = cmul2(cmul2(t4[j>>2], l0c[12][(j>>1)&1]), l0c[13][j&1]);
      a[j] = __floats2half2_rn(v.x, v.y);
    }
    scatter16(st, a, nb_of(tid, T_PA.t), CJ_PA);
  }
  __syncthreads();

  // ---- phase A: 4 reg + 6 lane layer-1 gates ----
  {
    __half2 a[16];
    gather16(st, a, tid);
    reg_gate<0>(a, load_gc(Utab+0*8), false);
    reg_gate<1>(a, load_gc(Utab+1*8), false);
    reg_gate<2>(a, load_gc(Utab+2*8), false);
    reg_gate<3>(a, load_gc(Utab+3*8), false);
    lane_gate<0,0u>(a, load_gc(Utab+4*8), (tid&1)!=0,  lane);
    lane_gate<1,0u>(a, load_gc(Utab+5*8), (tid&2)!=0,  lane);
    lane_gate<2,0u>(a, load_gc(Utab+6*8), (tid&4)!=0,  lane);
    lane_gate<3,0u>(a, load_gc(Utab+7*8), (tid&8)!=0,  lane);
    lane_gate<4,0u>(a, load_gc(Utab+8*8), (tid&16)!=0, lane);
    lane_gate<5,0u>(a, load_gc(Utab+9*8), (tid&32)!=0, lane);
    __syncthreads();                      // all reads done before cross-layout writes
    scatter16(st, a, nb_of(tid, T_AB.t), CJ_AB);
  }
  __syncthreads();

  // ---- phase B: 4 leftover layer-1 reg gates (runtime eps) + 6 layer-2 lane gates ----
  {
    __half2 a[16];
    gather16(st, a, tid);
    reg_gate<0>(a, load_gc(Utab+PL.BregGi[0]*8), (__builtin_popcount(PL.BregEps[0]&tid)&1)!=0);
    reg_gate<1>(a, load_gc(Utab+PL.BregGi[1]*8), (__builtin_popcount(PL.BregEps[1]&tid)&1)!=0);
    reg_gate<2>(a, load_gc(Utab+PL.BregGi[2]*8), (__builtin_popcount(PL.BregEps[2]&tid)&1)!=0);
    reg_gate<3>(a, load_gc(Utab+PL.BregGi[3]*8), (__builtin_popcount(PL.BregEps[3]&tid)&1)!=0);
    lane_gate<0,PL.BlanePi4[0]>(a, load_gc(Utab+PL.BlaneGi[0]*8), (tid&1)!=0,  lane);
    lane_gate<1,PL.BlanePi4[1]>(a, load_gc(Utab+PL.BlaneGi[1]*8), (tid&2)!=0,  lane);
    lane_gate<2,PL.BlanePi4[2]>(a, load_gc(Utab+PL.BlaneGi[2]*8), (tid&4)!=0,  lane);
    lane_gate<3,PL.BlanePi4[3]>(a, load_gc(Utab+PL.BlaneGi[3]*8), (tid&8)!=0,  lane);
    lane_gate<4,PL.BlanePi4[4]>(a, load_gc(Utab+PL.BlaneGi[4]*8), (tid&16)!=0, lane);
    lane_gate<5,PL.BlanePi4[5]>(a, load_gc(Utab+PL.BlaneGi[5]*8), (tid&32)!=0, lane);
    __syncthreads();
    scatter16(st, a, nb_of(tid, T_BC.t), CJ_BC);
  }
  __syncthreads();

  // ---- phase C: last 8 layer-2 gates, expectation from registers ----
  {
    __half2 a[16];
    gather16(st, a, tid);
    reg_gate<0>(a, load_gc(Utab+PL.CregGi[0]*8), (__builtin_popcount(PL.CregEps[0]&tid)&1)!=0);
    reg_gate<1>(a, load_gc(Utab+PL.CregGi[1]*8), (__builtin_popcount(PL.CregEps[1]&tid)&1)!=0);
    reg_gate<2>(a, load_gc(Utab+PL.CregGi[2]*8), (__builtin_popcount(PL.CregEps[2]&tid)&1)!=0);
    reg_gate<3>(a, load_gc(Utab+PL.CregGi[3]*8), (__builtin_popcount(PL.CregEps[3]&tid)&1)!=0);
    lane_gate<0,0u>(a, load_gc(Utab+PL.ClaneGi[0]*8),
        (((tid&1u)!=0) != ((__builtin_popcount(PL.ClaneEps[0]&tid)&1)!=0)), lane);
    lane_gate<1,0u>(a, load_gc(Utab+PL.ClaneGi[1]*8),
        (((tid&2u)!=0) != ((__builtin_popcount(PL.ClaneEps[1]&tid)&1)!=0)), lane);
    lane_gate<2,0u>(a, load_gc(Utab+PL.ClaneGi[2]*8),
        (((tid&4u)!=0) != ((__builtin_popcount(PL.ClaneEps[2]&tid)&1)!=0)), lane);
    lane_gate<3,0u>(a, load_gc(Utab+PL.ClaneGi[3]*8),
        (((tid&8u)!=0) != ((__builtin_popcount(PL.ClaneEps[3]&tid)&1)!=0)), lane);

    // ---- expectation via 4-bit Walsh-Hadamard on |a|^2 (f32) ----
    float p[16];
#pragma unroll
    for(int j=0;j<16;++j){
      float re = __low2float(a[j]), im = __high2float(a[j]);
      p[j] = fmaf(re, re, im*im);
    }
#pragma unroll
    for(int bstep=1; bstep<16; bstep<<=1){
#pragma unroll
      for(int j=0;j<16;++j){
        if(!(j & bstep)){
          float u = p[j], v = p[j|bstep];
          p[j] = u + v;
          p[j|bstep] = u - v;
        }
      }
    }
    const int wave = tid >> 6;
#pragma unroll
    for(int w=0;w<NQ;++w){
      float v = (__builtin_popcount(PL.ET[w]&tid)&1) ? -p[PL.EJ4[w]] : p[PL.EJ4[w]];
      v = xsum64(v, lane);
      if(lane==0) red[wave][w]=v;
    }
    __syncthreads();
    if(tid < NQ){
      float s=0.f;
#pragma unroll
      for(int wv=0; wv<NWAVES; ++wv) s += red[wv][tid];
      out[b*NQ + tid] = s;
    }
  }
}

}  // namespace

extern "C" void kernel_launch(void* const* d_in, const int* in_sizes, int n_in,
                              void* d_out, int out_size, void* d_ws, size_t ws_size,
                              hipStream_t stream) {
  const float* x   = (const float*)d_in[0];   // (batch, 14) f32
  const float* prm = (const float*)d_in[1];   // (3, 14, 3) f32
  float* out = (float*)d_out;                 // (batch, 14) f32
  const int batch = in_sizes[0] / NQ;
  qsim_kernel<<<batch, BLOCK, 0, stream>>>(x, prm, out);
}

// Round 18
// 36.980 us; speedup vs baseline: 3.6030x; 1.0738x over previous
//
#include <hip/hip_runtime.h>
#include <hip/hip_fp16.h>

namespace {

constexpr int NQ      = 14;
constexpr int NSTATES = 1 << NQ;
constexpr int BLOCK   = 1024;
constexpr int NWAVES  = BLOCK / 64;

// ---------------- compile-time GF(2) machinery (verified R2-R17) ----------------
constexpr unsigned cparity(unsigned x){ x^=x>>8; x^=x>>4; x^=x>>2; x^=x>>1; return x&1u; }

struct Mat { unsigned row[NQ]; unsigned col[NQ]; };

constexpr Mat m_after(int nr){
  Mat m{};
  for(int p=0;p<NQ;++p){ m.row[p]=1u<<p; m.col[p]=1u<<p; }
  for(int l=0;l<nr;++l)
    for(int q=0;q<NQ;++q){
      int cq=(q==NQ-1)?NQ-1:q, tq=(q==NQ-1)?0:q+1;
      int Pc=NQ-1-cq, Pt=NQ-1-tq;
      m.row[Pt]^=m.row[Pc]; m.col[Pc]^=m.col[Pt];
    }
  return m;
}

constexpr Mat M1=m_after(1), M2=m_after(2), M3=m_after(3);
constexpr unsigned amask(int q){ return M1.col[NQ-1-q]; }
constexpr unsigned arow (int q){ return M1.row[NQ-1-q]; }
constexpr unsigned bmask(int q){ return M2.col[NQ-1-q]; }
constexpr unsigned brow (int q){ return M2.row[NQ-1-q]; }

constexpr int rank_of(const unsigned* v, int n){
  unsigned a[24]{};
  for(int i=0;i<n;++i) a[i]=v[i];
  int r=0;
  for(int bit=15;bit>=0;--bit){
    int p=-1;
    for(int i=r;i<n;++i){ if((a[i]>>bit)&1){ p=i; break; } }
    if(p<0) continue;
    unsigned t=a[r]; a[r]=a[p]; a[p]=t;
    for(int i=0;i<n;++i) if(i!=r && ((a[i]>>bit)&1)) a[i]^=a[r];
    ++r;
  }
  return r;
}

struct Plan {
  unsigned A[14], B[14], C[14];
  int BlaneGi[6]; unsigned BlanePi4[6];
  int BregGi[4];  unsigned BregEps[4];
  int CregGi[4];  unsigned CregEps[4];
  int ClaneGi[4]; unsigned ClaneEps[4];
  unsigned EJ4[14], ET[14];
};

constexpr Plan make_plan(){
  Plan P{};
  for(int t=0;t<14;++t) P.A[t]=amask(t);
  for(int t=0;t<4;++t){ P.B[t]=amask(10+t); P.BregGi[t]=10+t; }
  bool used[14]{}; int picked[14]{}; int np=0;
  {
    unsigned cur[20]{}; int nc=0;
    for(int t=0;t<4;++t) cur[nc++]=P.B[t];
    for(int q=0;q<14 && np<10;++q){
      cur[nc]=bmask(q);
      if(rank_of(cur,nc+1)==nc+1){ ++nc; picked[np++]=q; used[q]=true; }
    }
  }
  for(int i=0;i<6;++i){ P.B[4+i]=bmask(picked[i]); P.BlaneGi[i]=14+picked[i]; }
  int wq[4]{}, un[4]{}; int nu=0;
  for(int i=0;i<4;++i){ wq[i]=picked[6+i]; P.B[10+i]=bmask(wq[i]); P.CregGi[i]=14+wq[i]; }
  for(int q=0;q<14;++q) if(!used[q]) un[nu++]=q;
  for(int i=0;i<4;++i) P.ClaneGi[i]=14+un[i];
  for(int i=0;i<4;++i){ unsigned m=0;
    for(int t=0;t<10;++t) m |= cparity(arow(10+i)&P.B[4+t])<<t;
    P.BregEps[i]=m; }
  for(int i=0;i<6;++i){ unsigned m=0;
    for(int t=0;t<4;++t) m |= cparity(brow(picked[i])&P.B[t])<<t;
    P.BlanePi4[i]=m; }
  for(int t=0;t<4;++t) P.C[t]=bmask(wq[t]);
  for(int t=0;t<4;++t) P.C[4+t]=bmask(un[t]);
  {
    unsigned cc[20]{}; int n=0;
    for(int t=0;t<8;++t) cc[n++]=P.C[t];
    int pos=8;
    for(int p=0;p<14 && pos<14;++p){
      cc[n]=1u<<p;
      if(rank_of(cc,n+1)==n+1){ P.C[pos]=1u<<p; ++n; ++pos; }
    }
  }
  for(int i=0;i<4;++i){ unsigned m=0;
    for(int t=0;t<10;++t) m |= cparity(brow(wq[i])&P.C[4+t])<<t;
    P.CregEps[i]=m; }
  for(int i=0;i<4;++i){ unsigned m=0;
    for(int t=0;t<10;++t){ if(t==i) continue; m |= cparity(brow(un[i])&P.C[4+t])<<t; }
    P.ClaneEps[i]=m; }
  for(int w=0;w<14;++w){
    unsigned R=M3.row[NQ-1-w]; unsigned mj=0, mt=0;
    for(int t=0;t<4;++t)  mj |= cparity(R&P.C[t])<<t;
    for(int t=0;t<10;++t) mt |= cparity(R&P.C[4+t])<<t;
    P.EJ4[w]=mj; P.ET[w]=mt;
  }
  return P;
}

constexpr Plan PL = make_plan();
static_assert(rank_of(PL.A,14)==14, "phase A map not bijective");
static_assert(rank_of(PL.B,14)==14, "phase B map not bijective");
static_assert(rank_of(PL.C,14)==14, "phase C map not bijective");

struct Inv { unsigned col[NQ]; };
constexpr Inv inv_basis(const unsigned* bas){
  unsigned vec[NQ]{}, cmb[NQ]{}; bool used[NQ]{}; int pivk[NQ]{};
  for(int k=0;k<NQ;++k){ vec[k]=bas[k]; cmb[k]=1u<<k; }
  for(int b=0;b<NQ;++b){
    int p=-1;
    for(int k=0;k<NQ;++k) if(!used[k] && ((vec[k]>>b)&1)){ p=k; break; }
    used[p]=true; pivk[b]=p;
    for(int k=0;k<NQ;++k) if(k!=p && ((vec[k]>>b)&1)){ vec[k]^=vec[p]; cmb[k]^=cmb[p]; }
  }
  Inv R{};
  for(int b=0;b<NQ;++b) R.col[b]=cmb[pivk[b]];
  return R;
}
constexpr bool check_inv(const unsigned* bas, const Inv& iv){
  for(int p=0;p<NQ;++p){
    unsigned s=0;
    for(int k=0;k<NQ;++k) if((iv.col[p]>>k)&1) s^=bas[k];
    if(s != (1u<<p)) return false;
  }
  return true;
}
constexpr Inv IA = inv_basis(PL.A), IB = inv_basis(PL.B), IC = inv_basis(PL.C);
static_assert(check_inv(PL.A, IA), "IA");
static_assert(check_inv(PL.B, IB), "IB");
static_assert(check_inv(PL.C, IC), "IC");

struct Trans { unsigned t[NQ]; };
constexpr Trans trans_phys(const Inv& iv){
  Trans T{};
  for(int p=0;p<NQ;++p) T.t[p]=iv.col[p];
  return T;
}
constexpr Trans trans_of(const unsigned* cur, const Inv& iv){
  Trans T{};
  for(int k=0;k<NQ;++k){
    unsigned c=0;
    for(int p=0;p<NQ;++p) if((cur[k]>>p)&1) c^=iv.col[p];
    T.t[k]=c;
  }
  return T;
}
constexpr Trans T_PA = trans_phys(IA);
constexpr Trans T_AB = trans_of(PL.A, IB);
constexpr Trans T_BC = trans_of(PL.B, IC);

struct CJ { unsigned v[16]; };
constexpr CJ mk_cj(const Trans& T){
  CJ c{};
  for(int j=0;j<16;++j){
    unsigned s=0;
    for(int b=0;b<4;++b) if((j>>b)&1) s^=T.t[b];
    c.v[j]=s;
  }
  return c;
}
constexpr CJ CJ_PA=mk_cj(T_PA), CJ_AB=mk_cj(T_AB), CJ_BC=mk_cj(T_BC);

// ---------------- packed-f16 complex helpers ----------------
__device__ __forceinline__ __half2 H2(unsigned u){ return __builtin_bit_cast(__half2, u); }
__device__ __forceinline__ unsigned U32(__half2 h){ return __builtin_bit_cast(unsigned, h); }
__device__ __forceinline__ unsigned hswap(unsigned u){ return __builtin_amdgcn_alignbit(u, u, 16); }

__device__ __forceinline__ float2 cmul2(float2 a, float2 b){
  return make_float2(fmaf(a.x, b.x, -(a.y * b.y)),
                     fmaf(a.x, b.y,  a.y * b.x));
}

struct GC { unsigned e[8]; };
__device__ __forceinline__ GC load_gc(const unsigned* __restrict__ g){
  const uint4* p = reinterpret_cast<const uint4*>(g);
  uint4 q0=p[0], q1=p[1];
  GC c;
  c.e[0]=q0.x; c.e[1]=q0.y; c.e[2]=q0.z; c.e[3]=q0.w;
  c.e[4]=q1.x; c.e[5]=q1.y; c.e[6]=q1.z; c.e[7]=q1.w;
  return c;
}

__device__ __forceinline__ void gpair(__half2& r0, __half2& r1, const unsigned (&m)[8],
                                      __half2 a0, __half2 a1){
  __half2 a0s = H2(hswap(U32(a0))), a1s = H2(hswap(U32(a1)));
  r0 = __hfma2(H2(m[0]),a0, __hfma2(H2(m[1]),a0s, __hfma2(H2(m[2]),a1, __hmul2(H2(m[3]),a1s))));
  r1 = __hfma2(H2(m[4]),a0, __hfma2(H2(m[5]),a0s, __hfma2(H2(m[6]),a1, __hmul2(H2(m[7]),a1s))));
}

template<int CTRL>
__device__ __forceinline__ unsigned dppu(unsigned x){
  return (unsigned)__builtin_amdgcn_update_dpp(0, (int)x, CTRL, 0xF, 0xF, true);
}
__device__ __forceinline__ unsigned x32u(unsigned x, unsigned lane){
  auto r = __builtin_amdgcn_permlane32_swap(x, x, false, false);
  return (lane & 32u) ? (unsigned)r[0] : (unsigned)r[1];
}
__device__ __forceinline__ unsigned x16u(unsigned x, unsigned lane){
#if __has_builtin(__builtin_amdgcn_permlane16_swap)
  auto r = __builtin_amdgcn_permlane16_swap(x, x, false, false);
  return (lane & 16u) ? (unsigned)r[0] : (unsigned)r[1];
#else
  return (unsigned)__builtin_amdgcn_ds_swizzle((int)x, 0x401F);
#endif
}
// K: 0:^1 1:^2 2:^4 3:^8 4:^16 5:^32
template<int K>
__device__ __forceinline__ unsigned xpart_u32(unsigned x, unsigned lane){
  if constexpr (K==0) return dppu<0xB1>(x);
  else if constexpr (K==1) return dppu<0x4E>(x);
  else if constexpr (K==2) return (unsigned)__builtin_amdgcn_ds_swizzle((int)x,0x101F);
  else if constexpr (K==3) return dppu<0x128>(x);
  else if constexpr (K==4) return x16u(x,lane);
  else return x32u(x,lane);
}

template<int BIT>
__device__ __forceinline__ void reg_gate(__half2 (&a)[16], const GC& c, bool eps){
  unsigned m[8];
#pragma unroll
  for(int i=0;i<8;++i) m[i] = eps ? c.e[i^6] : c.e[i];
#pragma unroll
  for(int v=0; v<16; ++v){
    if(!((v>>BIT)&1)){
      int w = v | (1<<BIT);
      __half2 n0, n1;
      gpair(n0, n1, m, a[v], a[w]);
      a[v]=n0; a[w]=n1;
    }
  }
}

template<int XK, unsigned PI4>
__device__ __forceinline__ void lane_gate(__half2 (&a)[16], const GC& c, bool sel, unsigned lane){
  unsigned ka0x = sel?c.e[6]:c.e[0], ka0n = sel?c.e[7]:c.e[1];
  unsigned kb0x = sel?c.e[4]:c.e[2], kb0n = sel?c.e[5]:c.e[3];
  unsigned ka1x = sel?c.e[0]:c.e[6], ka1n = sel?c.e[1]:c.e[7];
  unsigned kb1x = sel?c.e[2]:c.e[4], kb1n = sel?c.e[3]:c.e[5];
  unsigned th[16];
#pragma unroll
  for(int j=0;j<16;++j) th[j] = xpart_u32<XK>(U32(a[j]), lane);
#pragma unroll
  for(int j=0;j<16;++j){
    bool pi = (__builtin_popcount(PI4 & (unsigned)j) & 1) != 0;   // folds per unrolled j
    unsigned kax = pi?ka1x:ka0x, kan = pi?ka1n:ka0n;
    unsigned kbx = pi?kb1x:kb0x, kbn = pi?kb1n:kb0n;
    __half2 as  = H2(hswap(U32(a[j])));
    __half2 ths = H2(hswap(th[j]));
    a[j] = __hfma2(H2(kax),a[j], __hfma2(H2(kan),as, __hfma2(H2(kbx),H2(th[j]), __hmul2(H2(kbn),ths))));
  }
}

// in-register 64-lane butterfly sum (verified R12)
__device__ __forceinline__ float xsum64(float v, unsigned lane){
  v += __int_as_float((int)dppu<0xB1>((unsigned)__float_as_int(v)));
  v += __int_as_float((int)dppu<0x4E>((unsigned)__float_as_int(v)));
  v += __int_as_float(__builtin_amdgcn_ds_swizzle(__float_as_int(v),0x101F));
  v += __int_as_float((int)dppu<0x128>((unsigned)__float_as_int(v)));
  v += __int_as_float((int)x16u((unsigned)__float_as_int(v), lane));
  v += __int_as_float((int)x32u((unsigned)__float_as_int(v), lane));
  return v;
}

__device__ __forceinline__ unsigned nb_of(unsigned tid, const unsigned (&t)[NQ]){
  unsigned s=0;
#pragma unroll
  for(int k=0;k<10;++k) s ^= t[4+k] & (0u-((tid>>k)&1u));
  return s;
}

__device__ __forceinline__ void scatter16(unsigned* __restrict__ st, const __half2 (&a)[16],
                                          unsigned nb, const CJ& cj){
#pragma unroll
  for(int j=0;j<16;++j){
    unsigned d = nb ^ cj.v[j];
    st[d + (d>>4)] = U32(a[j]);
  }
}

// ---------------- kernel ----------------
__global__ __launch_bounds__(BLOCK, 4) void qsim_kernel(
    const float* __restrict__ x,
    const float* __restrict__ prm,
    float* __restrict__ out)
{
  __shared__ unsigned st[BLOCK*17];              // f16x2 state, 4B pad/thread (68 KiB)
  __shared__ alignas(16) unsigned Utab[28*8];    // packed gate constants (layers 1,2)
  __shared__ float2 l0c[NQ][2];
  __shared__ float  red[NWAVES][NQ];

  const int b = blockIdx.x;
  const unsigned tid = threadIdx.x;
  const unsigned lane = tid & 63u;

  // ---- gate table built in-kernel, packed f16 ----
  if(tid < 28){
    int t = tid;
    int l = 1 + t/NQ, q = t % NQ;
    float ax=prm[(l*NQ+q)*3+0], ay=prm[(l*NQ+q)*3+1], az=prm[(l*NQ+q)*3+2];
    float cx,sx,cy,sy,cz,sz;
    sincosf(0.5f*ax,&sx,&cx); sincosf(0.5f*ay,&sy,&cy); sincosf(0.5f*az,&sz,&cz);
    float2 M00=make_float2(cy*cx, sy*sx),  M01=make_float2(-sy*cx,-cy*sx);
    float2 M10=make_float2(sy*cx,-cy*sx),  M11=make_float2(cy*cx,-sy*sx);
    float2 ez =make_float2(cz,-sz), ezc=make_float2(cz,sz);
    float2 U00=cmul2(ez,M00), U01=cmul2(ez,M01), U10=cmul2(ezc,M10), U11=cmul2(ezc,M11);
    unsigned* U = &Utab[t*8];
    U[0]=U32(__floats2half2_rn( U00.x,U00.x)); U[1]=U32(__floats2half2_rn(-U00.y,U00.y));
    U[2]=U32(__floats2half2_rn( U01.x,U01.x)); U[3]=U32(__floats2half2_rn(-U01.y,U01.y));
    U[4]=U32(__floats2half2_rn( U10.x,U10.x)); U[5]=U32(__floats2half2_rn(-U10.y,U10.y));
    U[6]=U32(__floats2half2_rn( U11.x,U11.x)); U[7]=U32(__floats2half2_rn(-U11.y,U11.y));
  }
  // ---- layer-0 columns (x-dependent), f32 ----
  if(tid < NQ){
    int q = tid;
    float ax = prm[q*3+0] + x[b*NQ+q];
    float ay = prm[q*3+1], az = prm[q*3+2];
    float cx,sx,cy,sy,cz,sz;
    sincosf(0.5f*ax,&sx,&cx); sincosf(0.5f*ay,&sy,&cy); sincosf(0.5f*az,&sz,&cz);
    l0c[q][0] = cmul2(make_float2(cz,-sz), make_float2(cy*cx,  sy*sx));   // U00
    l0c[q][1] = cmul2(make_float2(cz, sz), make_float2(sy*cx, -cy*sx));   // U10
  }
  __syncthreads();

  // ---- init: product state (f32) packed once, scattered into phase-A layout ----
  {
    float2 p01 = cmul2(l0c[0][(tid>>9)&1],  l0c[1][(tid>>8)&1]);
    float2 p23 = cmul2(l0c[2][(tid>>7)&1],  l0c[3][(tid>>6)&1]);
    float2 p45 = cmul2(l0c[4][(tid>>5)&1],  l0c[5][(tid>>4)&1]);
    float2 p67 = cmul2(l0c[6][(tid>>3)&1],  l0c[7][(tid>>2)&1]);
    float2 p89 = cmul2(l0c[8][(tid>>1)&1],  l0c[9][tid&1]);
    float2 Pk  = cmul2(cmul2(cmul2(p01,p23), cmul2(p45,p67)), p89);
    float2 t2[2], t4[4];
    t2[0]=cmul2(Pk,l0c[10][0]); t2[1]=cmul2(Pk,l0c[10][1]);
#pragma unroll
    for(int i=0;i<2;++i){ t4[2*i]=cmul2(t2[i],l0c[11][0]); t4[2*i+1]=cmul2(t2[i],l0c[11][1]); }
    __half2 a[16];
#pragma unroll
    for(int j=0;j<16;++j){
      float2 v = cmul2(cmul2(t4[j>>2], l0c[12][(j>>1)&1]), l0c[13][j&1]);
      a[j] = __floats2half2_rn(v.x, v.y);
    }
    scatter16(st, a, nb_of(tid, T_PA.t), CJ_PA);
  }
  __syncthreads();

  // ---- phase A: 4 reg + 6 lane layer-1 gates ----
  {
    __half2 a[16];
    const int rb = (int)tid*17;
#pragma unroll
    for(int j=0;j<16;++j) a[j] = H2(st[rb + j]);
    reg_gate<0>(a, load_gc(Utab+0*8), false);
    reg_gate<1>(a, load_gc(Utab+1*8), false);
    reg_gate<2>(a, load_gc(Utab+2*8), false);
    reg_gate<3>(a, load_gc(Utab+3*8), false);
    lane_gate<0,0u>(a, load_gc(Utab+4*8), (tid&1)!=0,  lane);
    lane_gate<1,0u>(a, load_gc(Utab+5*8), (tid&2)!=0,  lane);
    lane_gate<2,0u>(a, load_gc(Utab+6*8), (tid&4)!=0,  lane);
    lane_gate<3,0u>(a, load_gc(Utab+7*8), (tid&8)!=0,  lane);
    lane_gate<4,0u>(a, load_gc(Utab+8*8), (tid&16)!=0, lane);
    lane_gate<5,0u>(a, load_gc(Utab+9*8), (tid&32)!=0, lane);
    __syncthreads();                      // all reads done before cross-layout writes
    scatter16(st, a, nb_of(tid, T_AB.t), CJ_AB);
  }
  __syncthreads();

  // ---- phase B: 4 leftover layer-1 reg gates (runtime eps) + 6 layer-2 lane gates ----
  {
    __half2 a[16];
    const int rb = (int)tid*17;
#pragma unroll
    for(int j=0;j<16;++j) a[j] = H2(st[rb + j]);
    reg_gate<0>(a, load_gc(Utab+PL.BregGi[0]*8), (__builtin_popcount(PL.BregEps[0]&tid)&1)!=0);
    reg_gate<1>(a, load_gc(Utab+PL.BregGi[1]*8), (__builtin_popcount(PL.BregEps[1]&tid)&1)!=0);
    reg_gate<2>(a, load_gc(Utab+PL.BregGi[2]*8), (__builtin_popcount(PL.BregEps[2]&tid)&1)!=0);
    reg_gate<3>(a, load_gc(Utab+PL.BregGi[3]*8), (__builtin_popcount(PL.BregEps[3]&tid)&1)!=0);
    lane_gate<0,PL.BlanePi4[0]>(a, load_gc(Utab+PL.BlaneGi[0]*8), (tid&1)!=0,  lane);
    lane_gate<1,PL.BlanePi4[1]>(a, load_gc(Utab+PL.BlaneGi[1]*8), (tid&2)!=0,  lane);
    lane_gate<2,PL.BlanePi4[2]>(a, load_gc(Utab+PL.BlaneGi[2]*8), (tid&4)!=0,  lane);
    lane_gate<3,PL.BlanePi4[3]>(a, load_gc(Utab+PL.BlaneGi[3]*8), (tid&8)!=0,  lane);
    lane_gate<4,PL.BlanePi4[4]>(a, load_gc(Utab+PL.BlaneGi[4]*8), (tid&16)!=0, lane);
    lane_gate<5,PL.BlanePi4[5]>(a, load_gc(Utab+PL.BlaneGi[5]*8), (tid&32)!=0, lane);
    __syncthreads();
    scatter16(st, a, nb_of(tid, T_BC.t), CJ_BC);
  }
  __syncthreads();

  // ---- phase C: last 8 layer-2 gates, expectation from registers ----
  {
    __half2 a[16];
    const int rb = (int)tid*17;
#pragma unroll
    for(int j=0;j<16;++j) a[j] = H2(st[rb + j]);
    reg_gate<0>(a, load_gc(Utab+PL.CregGi[0]*8), (__builtin_popcount(PL.CregEps[0]&tid)&1)!=0);
    reg_gate<1>(a, load_gc(Utab+PL.CregGi[1]*8), (__builtin_popcount(PL.CregEps[1]&tid)&1)!=0);
    reg_gate<2>(a, load_gc(Utab+PL.CregGi[2]*8), (__builtin_popcount(PL.CregEps[2]&tid)&1)!=0);
    reg_gate<3>(a, load_gc(Utab+PL.CregGi[3]*8), (__builtin_popcount(PL.CregEps[3]&tid)&1)!=0);
    lane_gate<0,0u>(a, load_gc(Utab+PL.ClaneGi[0]*8),
        (((tid&1u)!=0) != ((__builtin_popcount(PL.ClaneEps[0]&tid)&1)!=0)), lane);
    lane_gate<1,0u>(a, load_gc(Utab+PL.ClaneGi[1]*8),
        (((tid&2u)!=0) != ((__builtin_popcount(PL.ClaneEps[1]&tid)&1)!=0)), lane);
    lane_gate<2,0u>(a, load_gc(Utab+PL.ClaneGi[2]*8),
        (((tid&4u)!=0) != ((__builtin_popcount(PL.ClaneEps[2]&tid)&1)!=0)), lane);
    lane_gate<3,0u>(a, load_gc(Utab+PL.ClaneGi[3]*8),
        (((tid&8u)!=0) != ((__builtin_popcount(PL.ClaneEps[3]&tid)&1)!=0)), lane);

    // ---- expectation via 4-bit Walsh-Hadamard on |a|^2 (f32) ----
    float p[16];
#pragma unroll
    for(int j=0;j<16;++j){
      float re = __low2float(a[j]), im = __high2float(a[j]);
      p[j] = fmaf(re, re, im*im);
    }
#pragma unroll
    for(int bstep=1; bstep<16; bstep<<=1){
#pragma unroll
      for(int j=0;j<16;++j){
        if(!(j & bstep)){
          float u = p[j], v = p[j|bstep];
          p[j] = u + v;
          p[j|bstep] = u - v;
        }
      }
    }
    const int wave = tid >> 6;
#pragma unroll
    for(int w=0;w<NQ;++w){
      float v = (__builtin_popcount(PL.ET[w]&tid)&1) ? -p[PL.EJ4[w]] : p[PL.EJ4[w]];
      v = xsum64(v, lane);
      if(lane==0) red[wave][w]=v;
    }
    __syncthreads();
    if(tid < NQ){
      float s=0.f;
#pragma unroll
      for(int wv=0; wv<NWAVES; ++wv) s += red[wv][tid];
      out[b*NQ + tid] = s;
    }
  }
}

}  // namespace

extern "C" void kernel_launch(void* const* d_in, const int* in_sizes, int n_in,
                              void* d_out, int out_size, void* d_ws, size_t ws_size,
                              hipStream_t stream) {
  const float* x   = (const float*)d_in[0];   // (batch, 14) f32
  const float* prm = (const float*)d_in[1];   // (3, 14, 3) f32
  float* out = (float*)d_out;                 // (batch, 14) f32
  const int batch = in_sizes[0] / NQ;
  qsim_kernel<<<batch, BLOCK, 0, stream>>>(x, prm, out);
}